// Round 10
// baseline (211.114 us; speedup 1.0000x reference)
//
#include <hip/hip_runtime.h>

#define BB 16
#define LL 4096
#define DD 64

typedef const float* __restrict__ cfp;
typedef float* __restrict__ fp;
typedef const ushort* __restrict__ cup;
typedef ushort* __restrict__ up;

typedef __attribute__((ext_vector_type(8))) short bf16x8;
typedef __attribute__((ext_vector_type(4))) float f32x4;
#define MFMA16(a, b, c) __builtin_amdgcn_mfma_f32_16x16x32_bf16(a, b, c, 0, 0, 0)

__device__ __forceinline__ f32x4 zf4(){ f32x4 z; z[0]=0.f; z[1]=0.f; z[2]=0.f; z[3]=0.f; return z; }

union frag_u { bf16x8 v; uint2 u2[2]; uint u[4]; };

__device__ __forceinline__ float4 ld4(const float* p){ return *reinterpret_cast<const float4*>(p); }

__device__ __forceinline__ ushort f2bf(float f){
  uint u = __float_as_uint(f);
  return (ushort)((u + 0x7FFFu + ((u >> 16) & 1u)) >> 16);   // RNE
}
__device__ __forceinline__ float bf2f(ushort u){
  return __uint_as_float(((uint)u) << 16);
}
__device__ __forceinline__ uint packf2(float a, float b){
  return (uint)f2bf(a) | ((uint)f2bf(b) << 16);
}
__device__ __forceinline__ uint2 pack4(float4 v){
  return make_uint2(packf2(v.x, v.y), packf2(v.z, v.w));
}
__device__ __forceinline__ bf16x8 ldfrag(const ushort* p){ return *reinterpret_cast<const bf16x8*>(p); }

// ---------------- weight packing into bf16 B-fragments (+ emb) ----------------
__global__ __launch_bounds__(256) void k_pack(cfp wq, cfp wk, cfp wv, cfp getv, cfp wo,
                                              cfp fw1, cfp fw2, cfp embw,
                                              up dst, up dstE) {
  int layer = blockIdx.y;
  int e = blockIdx.x*256 + threadIdx.x;        // e < 40960
  if (e >= 36864) {
    int rem = e - 36864;
    int j = rem & 7, lane = (rem >> 3) & 63, rest = rem >> 9;
    int nt = rest & 3, ks = rest >> 2;
    int k = ks*32 + ((lane >> 4) << 3) + j, n = nt*16 + (lane & 15);
    dstE[rem] = f2bf(embw[k*64 + n]);
    return;
  }
  const float* W; int N, rem;
  if (e < 20480) {
    int mm = e >> 12; rem = e & 4095;
    W = (mm==0?wq: mm==1?wk: mm==2?wv: mm==3?getv: wo) + layer*4096; N = 64;
  } else if (e < 28672) {
    rem = e - 20480; W = fw1 + layer*8192; N = 128;
  } else {
    rem = e - 28672; W = fw2 + layer*8192; N = 64;
  }
  int NT = N >> 4;
  int j = rem & 7, lane = (rem >> 3) & 63, rest = rem >> 9;
  int nt = rest % NT, ks = rest / NT;
  int k = ks*32 + ((lane >> 4) << 3) + j, n = nt*16 + (lane & 15);
  dst[(size_t)layer*36864 + e] = f2bf(W[(size_t)k*N + n]);
}

// ---------------- pooling of raw input x (16 chunks) ----------------
__global__ __launch_bounds__(256) void k_pool_part(cfp h, fp pp) {
  int b = blockIdx.x, gblk = blockIdx.y, t = threadIdx.x;
  int c = t & 63, r = t >> 6;
  const float* base = h + ((size_t)b*LL + (size_t)gblk*256)*64;
  float acc = 0.f;
  for (int l = r; l < 256; l += 4) acc += base[(size_t)l*64 + c];
  __shared__ float red[4][64];
  red[r][c] = acc; __syncthreads();
  if (t < 64) pp[(b*16 + gblk)*64 + t] = red[0][t]+red[1][t]+red[2][t]+red[3][t];
}

// ---------------- tiny MLP (pooled -> 3-way softmax attn), block-uniform ----------------
__device__ __forceinline__ void tiny_mlp3(int t, const float* __restrict__ pooled,
                                          cfp w1, cfp b1, cfp w2, cfp b2,
                                          float* attn, float* hdn) {
  if (t < 16) {
    float a = b1[t];
    for (int c = 0; c < 64; ++c) a += pooled[c]*w1[t*64 + c];
    hdn[t] = fmaxf(a, 0.f);
  }
  __syncthreads();
  if (t < 3) {
    float a = b2[t];
    for (int j = 0; j < 16; ++j) a += hdn[j]*w2[t*16 + j];
    attn[t] = a;
  }
  __syncthreads();
  if (t == 0) {
    float m = fmaxf(attn[0], fmaxf(attn[1], attn[2]));
    float e0 = __expf(attn[0]-m), e1 = __expf(attn[1]-m), e2 = __expf(attn[2]-m);
    float s = e0+e1+e2;
    attn[0]=e0/s; attn[1]=e1/s; attn[2]=e2/s;
  }
  __syncthreads();
}

// ---------------- analytic attn-weight chain (all 3 stages, no conv needed) ----------------
// Uses linearity of zero-padded 3-tap conv:
//   S_out = W0*(S - in[L-1]) + W1*S + W2*(S - in[0]);  out[0] = W1*in[0] + W2*in[1];
//   out[L-1] = W0*in[L-2] + W1*in[L-1].
__global__ __launch_bounds__(256) void k_attns(cfp pp, cfp x, cfp dcw1, cfp dcb1,
                                               cfp dcw2, cfp dcb2, cfp dck, fp attns) {
  int b = blockIdx.x, t = threadIdx.x;
  __shared__ float S[64], e0v[64], e1v[64], em0[64], em1[64];
  __shared__ float h10[64], h1m[64], Sn[64];
  __shared__ float pooled[64], hdn[16], attn[3], redu[256];
  const float* xb = x + (size_t)b*LL*64;
  if (t < 64) {
    float s = 0.f;
    for (int g = 0; g < 16; ++g) s += pp[((size_t)b*16 + g)*64 + t];
    S[t] = s;
    pooled[t] = s * (1.f/4096.f);
    e0v[t] = xb[t];
    e1v[t] = xb[64 + t];
    em0[t] = xb[(size_t)(LL-2)*64 + t];
    em1[t] = xb[(size_t)(LL-1)*64 + t];
  }
  __syncthreads();
  // ---- stage 0 ----
  tiny_mlp3(t, pooled, dcw1, dcb1, dcw2, dcb2, attn, hdn);
  if (t < 3) attns[b*9 + t] = attn[t];
  {
    int co = t & 63, q = t >> 6;
    float a0 = attn[0], a1 = attn[1], a2 = attn[2];
    float ph0=0.f, phm=0.f, pS=0.f;
    cfp kb = dck;
    for (int ci = q*16; ci < q*16 + 16; ++ci) {
      size_t base = ((size_t)co*64 + ci)*9 + 1;
      float k00=kb[base],       k01=kb[base+3],       k02=kb[base+6];
      float k10=kb[base+36864], k11=kb[base+36867],   k12=kb[base+36870];
      float k20=kb[base+73728], k21=kb[base+73731],   k22=kb[base+73734];
      float w0 = a0*k00 + a1*k10 + a2*k20;
      float w1 = a0*k01 + a1*k11 + a2*k21;
      float w2 = a0*k02 + a1*k12 + a2*k22;
      ph0 += w1*e0v[ci] + w2*e1v[ci];
      phm += w0*em0[ci] + w1*em1[ci];
      pS  += w0*(S[ci]-em1[ci]) + w1*S[ci] + w2*(S[ci]-e0v[ci]);
    }
    redu[t] = ph0; __syncthreads();
    if (t < 64) h10[t] = redu[t]+redu[64+t]+redu[128+t]+redu[192+t];
    __syncthreads();
    redu[t] = phm; __syncthreads();
    if (t < 64) h1m[t] = redu[t]+redu[64+t]+redu[128+t]+redu[192+t];
    __syncthreads();
    redu[t] = pS; __syncthreads();
    if (t < 64) {
      Sn[t] = redu[t]+redu[64+t]+redu[128+t]+redu[192+t];
      pooled[t] = Sn[t] * (1.f/4096.f);
    }
    __syncthreads();
  }
  // ---- stage 1 ----
  tiny_mlp3(t, pooled, dcw1+1024, dcb1+16, dcw2+48, dcb2+3, attn, hdn);
  if (t < 3) attns[b*9 + 3 + t] = attn[t];
  {
    int co = t & 63, q = t >> 6;
    float a0 = attn[0], a1 = attn[1], a2 = attn[2];
    float pS = 0.f;
    cfp kb = dck + 110592;
    for (int ci = q*16; ci < q*16 + 16; ++ci) {
      size_t base = ((size_t)co*64 + ci)*9 + 1;
      float k00=kb[base],       k01=kb[base+3],       k02=kb[base+6];
      float k10=kb[base+36864], k11=kb[base+36867],   k12=kb[base+36870];
      float k20=kb[base+73728], k21=kb[base+73731],   k22=kb[base+73734];
      float w0 = a0*k00 + a1*k10 + a2*k20;
      float w1 = a0*k01 + a1*k11 + a2*k21;
      float w2 = a0*k02 + a1*k12 + a2*k22;
      pS += w0*(Sn[ci]-h1m[ci]) + w1*Sn[ci] + w2*(Sn[ci]-h10[ci]);
    }
    redu[t] = pS; __syncthreads();
    if (t < 64) pooled[t] = (redu[t]+redu[64+t]+redu[128+t]+redu[192+t]) * (1.f/4096.f);
    __syncthreads();
  }
  // ---- stage 2 ----
  tiny_mlp3(t, pooled, dcw1+2048, dcb1+32, dcw2+96, dcb2+6, attn, hdn);
  if (t < 3) attns[b*9 + 6 + t] = attn[t];
}

// ---------------- effective-kernel fragment writer (all 3 stages) ----------------
__global__ __launch_bounds__(256) void k_wefff(cfp attns, cfp dck, up weffB) {
  int b = blockIdx.x, stage = blockIdx.y >> 3, slice = blockIdx.y & 7, t = threadIdx.x;
  float a0 = attns[b*9 + stage*3 + 0];
  float a1 = attns[b*9 + stage*3 + 1];
  float a2 = attns[b*9 + stage*3 + 2];
  cfp kern = dck + (size_t)stage*110592;
  int e0i = slice*1536;
  for (int e = e0i + t; e < e0i + 1536; e += 256) {
    int j = e & 7, lane = (e >> 3) & 63, nt = (e >> 9) & 3, ks = e >> 11;
    int k = ks*32 + ((lane >> 4) << 3) + j;
    int co = nt*16 + (lane & 15);
    int kh = k >> 6, ci = k & 63;
    size_t base = ((size_t)co*64 + ci)*9 + kh*3 + 1;     // kw=1 only (W=1 with pad)
    float v = a0*kern[base] + a1*kern[base + 36864] + a2*kern[base + 2*36864];
    weffB[((size_t)stage*16 + b)*12288 + e] = f2bf(v);
  }
}

// ---------------- conv MFMA core ----------------
__device__ __forceinline__ void conv_mfma(const ushort* Ts, const ushort* wb,
                                          int band, int lr, int lg, int l, f32x4 acc[4]) {
  #pragma unroll
  for (int nt = 0; nt < 4; ++nt) acc[nt] = zf4();
  #pragma unroll
  for (int ks = 0; ks < 6; ++ks) {
    int k8 = ks*32 + lg*8;
    int kh = k8 >> 6, ci = k8 & 63;
    bf16x8 a = ldfrag(Ts + (band + lr + kh)*72 + ci);
    #pragma unroll
    for (int nt = 0; nt < 4; ++nt)
      acc[nt] = MFMA16(a, ldfrag(wb + ((ks*4+nt)*64 + l)*8), acc[nt]);
  }
}

// ---------------- fused conv stem: 3 dynamic-conv stages + emb GEMM, halo'd ----------------
// LDS rows r <-> global rows n0-4+r. x valid r in [1,70].
// stage0 writes rows [2,81] (bands {2,18,34,50,66}); rows with g outside [0,LL) forced to 0.
// stage1 writes rows [3,82] (bands {3,19,35,51,67}); same zero-forcing.
// stage2 writes rows [4,67] (bands {4,20,36,52}) — always in-range.
__global__ __launch_bounds__(256) void k_convF(cfp x, cup weffB, cup wE, cfp embb,
                                               up houtB, fp pp) {
  int b = blockIdx.x, wblk = blockIdx.y, t = threadIdx.x;
  int n0 = wblk*64;
  __shared__ ushort TsA[84*72];
  __shared__ ushort TsB[84*72];
  __shared__ float red[64*17];
  int w = t >> 6, l = t & 63, lr = l & 15, lg = l >> 4;

  for (int idx = t; idx < 1344; idx += 256) {
    int r = idx >> 4, c4 = (idx & 15)*4;
    int g = n0 - 4 + r;
    float4 v = make_float4(0.f,0.f,0.f,0.f);
    if (r >= 1 && r <= 70 && g >= 0 && g < LL) v = ld4(x + ((size_t)b*LL + g)*64 + c4);
    *(uint2*)(TsA + r*72 + c4) = pack4(v);
  }
  for (int idx = t; idx < 32; idx += 256) {       // zero TsB guard rows 82,83
    int r = 82 + (idx >> 4), c4 = (idx & 15)*4;
    *(uint2*)(TsB + r*72 + c4) = make_uint2(0u,0u);
  }
  __syncthreads();

  // ---- stage 0: TsA -> TsB (zero-force rows outside [0,LL)) ----
  {
    const ushort* wb = weffB + (size_t)b*12288;
    for (int bi = w; bi < 5; bi += 4) {
      int band = 2 + bi*16;
      f32x4 acc[4];
      conv_mfma(TsA, wb, band - 1, lr, lg, l, acc);
      #pragma unroll
      for (int nt = 0; nt < 4; ++nt)
        #pragma unroll
        for (int reg = 0; reg < 4; ++reg) {
          int row = band + lg*4 + reg;
          int g = n0 - 4 + row;
          float v = (g >= 0 && g < LL) ? acc[nt][reg] : 0.f;
          TsB[row*72 + nt*16 + lr] = f2bf(v);
        }
    }
  }
  __syncthreads();
  // ---- stage 1: TsB -> TsA (zero-force rows outside [0,LL)) ----
  {
    const ushort* wb = weffB + (size_t)(16 + b)*12288;
    for (int bi = w; bi < 5; bi += 4) {
      int band = 3 + bi*16;
      f32x4 acc[4];
      conv_mfma(TsB, wb, band - 1, lr, lg, l, acc);
      #pragma unroll
      for (int nt = 0; nt < 4; ++nt)
        #pragma unroll
        for (int reg = 0; reg < 4; ++reg) {
          int row = band + lg*4 + reg;
          int g = n0 - 4 + row;
          float v = (g >= 0 && g < LL) ? acc[nt][reg] : 0.f;
          TsA[row*72 + nt*16 + lr] = f2bf(v);
        }
    }
  }
  __syncthreads();
  // ---- stage 2: TsA -> TsB (exactly 4 bands, all in-range) ----
  {
    const ushort* wb = weffB + (size_t)(32 + b)*12288;
    int band = 4 + w*16;
    f32x4 acc[4];
    conv_mfma(TsA, wb, band - 1, lr, lg, l, acc);
    #pragma unroll
    for (int nt = 0; nt < 4; ++nt)
      #pragma unroll
      for (int reg = 0; reg < 4; ++reg)
        TsB[(band + lg*4 + reg)*72 + nt*16 + lr] = f2bf(acc[nt][reg]);
  }
  __syncthreads();
  // ---- emb GEMM on stage-2 rows; bounce via TsA for coalesced store ----
  {
    int band = 4 + w*16;
    f32x4 ea[4];
    #pragma unroll
    for (int nt = 0; nt < 4; ++nt) ea[nt] = zf4();
    #pragma unroll
    for (int ks = 0; ks < 2; ++ks) {
      bf16x8 a = ldfrag(TsB + (band + lr)*72 + ks*32 + lg*8);
      #pragma unroll
      for (int nt = 0; nt < 4; ++nt)
        ea[nt] = MFMA16(a, ldfrag(wE + ((ks*4+nt)*64 + l)*8), ea[nt]);
    }
    #pragma unroll
    for (int nt = 0; nt < 4; ++nt) {
      int col = nt*16 + lr;
      float bc = embb[col], part = 0.f;
      #pragma unroll
      for (int reg = 0; reg < 4; ++reg) {
        int row = band + lg*4 + reg;
        float y = ea[nt][reg] + bc;
        TsA[row*72 + col] = f2bf(y);
        part += y;
      }
      red[col*17 + w*4 + lg] = part;
    }
  }
  __syncthreads();
  for (int idx = t; idx < 512; idx += 256) {
    int r = idx >> 3, c8 = (idx & 7)*8;
    *(uint4*)(houtB + ((size_t)b*LL + n0 + r)*64 + c8) = *(const uint4*)(TsA + (r+4)*72 + c8);
  }
  if (t < 64) {
    float s = 0.f;
    #pragma unroll
    for (int g = 0; g < 16; ++g) s += red[t*17 + g];
    pp[((size_t)b*64 + wblk)*64 + t] = s;
  }
}

// ---------------- agent attention: chunked scores + weighted-sum partials (bf16 h) ----------------
__global__ __launch_bounds__(256) void k_agent2(cup h16, cfp anb, cfp pp,
                                                fp pm, fp pe, fp pw) {
  int b = blockIdx.x, ch = blockIdx.y, t = threadIdx.x;
  int w = t >> 6, l = t & 63;
  __shared__ float means_s[64];
  __shared__ float sc[8][258];
  __shared__ float red4[4][64];
  __shared__ float esp[8][33];
  __shared__ float mcs[8], ess[8];
  __shared__ float wred[4][8][64];
  {
    float acc = 0.f;
    for (int c = w; c < 64; c += 4) acc += pp[((size_t)b*64 + c)*64 + l];
    red4[w][l] = acc;
  }
  __syncthreads();
  if (t < 64) means_s[t] = (red4[0][t]+red4[1][t]+red4[2][t]+red4[3][t])
                           * (1.f/4096.f) * 0.35355339059327373f;
  __syncthreads();
  const ushort* hb = h16 + ((size_t)b*LL + (size_t)ch*256)*64;
  int g8 = l >> 3, k8 = l & 7;
  float ms8[8];
  #pragma unroll
  for (int j = 0; j < 8; ++j) ms8[j] = means_s[k8*8 + j];
  #pragma unroll
  for (int it = 0; it < 8; ++it) {
    int n = w*64 + it*8 + g8;
    uint4 hv = *(const uint4*)(hb + (size_t)n*64 + k8*8);
    float d = bf2f((ushort)(hv.x & 0xffffu))*ms8[0] + bf2f((ushort)(hv.x >> 16))*ms8[1]
            + bf2f((ushort)(hv.y & 0xffffu))*ms8[2] + bf2f((ushort)(hv.y >> 16))*ms8[3]
            + bf2f((ushort)(hv.z & 0xffffu))*ms8[4] + bf2f((ushort)(hv.z >> 16))*ms8[5]
            + bf2f((ushort)(hv.w & 0xffffu))*ms8[6] + bf2f((ushort)(hv.w >> 16))*ms8[7];
    sc[k8][n] = d;
  }
  __syncthreads();
  int hh = t >> 5, j0 = (t & 31) * 8;
  const float* ab = anb + (size_t)hh*LL + ch*256 + j0;
  float loc[8];
  float mx = -1e30f;
  #pragma unroll
  for (int k = 0; k < 8; ++k) {
    loc[k] = sc[hh][j0 + k] + ab[k];
    mx = fmaxf(mx, loc[k]);
  }
  esp[hh][t & 31] = mx;
  __syncthreads();
  if (t < 8) {
    float m = -1e30f;
    for (int k = 0; k < 32; ++k) m = fmaxf(m, esp[t][k]);
    mcs[t] = m;
  }
  __syncthreads();
  {
    float M = mcs[hh], s = 0.f;
    #pragma unroll
    for (int k = 0; k < 8; ++k) {
      float e = __expf(loc[k] - M);
      sc[hh][j0 + k] = e;
      s += e;
    }
    esp[hh][t & 31] = s;
  }
  __syncthreads();
  if (t < 8) {
    float s = 0.f;
    for (int k = 0; k < 32; ++k) s += esp[t][k];
    ess[t] = s;
  }
  float acc8[8] = {};
  for (int i = 0; i < 64; ++i) {
    int n = w*64 + i;
    float xv = bf2f(hb[(size_t)n*64 + l]);
    #pragma unroll
    for (int q = 0; q < 8; ++q) acc8[q] = fmaf(sc[q][n], xv, acc8[q]);
  }
  __syncthreads();
  #pragma unroll
  for (int q = 0; q < 8; ++q) wred[w][q][l] = acc8[q];
  __syncthreads();
  for (int o = t; o < 512; o += 256) {
    int q = o >> 6, ll = o & 63;
    pw[(((size_t)b*16 + ch)*8 + q)*64 + ll] =
        wred[0][q][ll]+wred[1][q][ll]+wred[2][q][ll]+wred[3][q][ll];
  }
  if (t < 8) {
    pe[((size_t)b*16 + ch)*8 + t] = ess[t];
    pm[((size_t)b*16 + ch)*8 + t] = mcs[t];
  }
}

// ================= fused layer kernel (all-MFMA, agfin folded, bf16 in; templated out) =================
template<bool OUT_BF16>
__global__ __launch_bounds__(256, 4) void k_layer(
    cup h16, cfp pm, cfp pe, cfp pw, cfp getv, cfp getvb, cup wB,
    cfp bq, cfp bk, cfp bv, cfp bo,
    cfp g1, cfp be1, cfp b1, cfp b2, cfp g2, cfp be2,
    fp Y, up Y16, fp pp) {
  __shared__ float smem[10048];
  ushort* HsB  = (ushort*)(smem);
  ushort* Qp   = (ushort*)(smem + 2304);
  ushort* Kp   = (ushort*)(smem + 4864);
  ushort* Vt   = (ushort*)(smem + 7424);
  float*  sums = smem + 9728;
  float*  agvs = smem + 9984;
  float*  wm   = smem + 7424;          // [8][65] alias Vt (prologue only)
  float*  msden= smem + 7944;          // 16 fl
  ushort* OB   = (ushort*)(smem + 7424);
  float*  red  = smem + 7424;
  ushort* HidB = (ushort*)(smem + 2304);

  int t = threadIdx.x;
  size_t n0 = (size_t)blockIdx.x*64;
  int b = (int)(n0 >> 12);
  int w = t >> 6, l = t & 63, band = w*16, lr = l & 15, lg = l >> 4;

  #pragma unroll
  for (int it = 0; it < 2; ++it) {
    int idx = it*256 + t, r = idx >> 3, c8 = (idx & 7)*8;
    *(uint4*)(HsB + r*72 + c8) = *(const uint4*)(h16 + (n0 + r)*64 + c8);
  }
  if (t < 8) {
    float M = -1e30f;
    for (int c = 0; c < 16; ++c) M = fmaxf(M, pm[((size_t)b*16+c)*8 + t]);
    float d = 0.f;
    for (int c = 0; c < 16; ++c)
      d += pe[((size_t)b*16+c)*8 + t] * __expf(pm[((size_t)b*16+c)*8 + t] - M);
    msden[t] = M; msden[8+t] = d;
  }
  __syncthreads();
  for (int o = t; o < 512; o += 256) {
    int q = o >> 6, l2 = o & 63;
    float M = msden[q], s = 0.f;
    for (int c = 0; c < 16; ++c)
      s += pw[(((size_t)b*16+c)*8 + q)*64 + l2] * __expf(pm[((size_t)b*16+c)*8 + q] - M);
    wm[q*65 + l2] = s / msden[8+q];
  }
  __syncthreads();
  if (t < 64) {
    int q = t >> 3;
    float a = getvb[t];
    for (int c = 0; c < 64; ++c) a = fmaf(wm[q*65 + c], getv[c*64 + t], a);
    agvs[t] = a;
  }
  __syncthreads();

  // ---- Q,K,V,lepe MFMA GEMMs ----
  f32x4 ka[4], va[4], qa[4], la[4];
  #pragma unroll
  for (int nt = 0; nt < 4; ++nt) {
    ka[nt] = zf4(); va[nt] = zf4(); qa[nt] = zf4(); la[nt] = zf4();
  }
  #pragma unroll
  for (int ks = 0; ks < 2; ++ks) {
    bf16x8 a = ldfrag(HsB + (band + lr)*72 + ks*32 + lg*8);
    #pragma unroll
    for (int nt = 0; nt < 4; ++nt) {
      int fo = ((ks*4 + nt)*64 + l)*8;
      qa[nt] = MFMA16(a, ldfrag(wB + fo),         qa[nt]);
      ka[nt] = MFMA16(a, ldfrag(wB + 4096 + fo),  ka[nt]);
      va[nt] = MFMA16(a, ldfrag(wB + 8192 + fo),  va[nt]);
      la[nt] = MFMA16(a, ldfrag(wB + 12288 + fo), la[nt]);
    }
  }
  #pragma unroll
  for (int nt = 0; nt < 4; ++nt) {
    int col = nt*16 + lr;
    float bkc = bk[col], bvc = bv[col], bqc = bq[col];
    #pragma unroll
    for (int reg = 0; reg < 4; ++reg) {
      int tok = band + 4*lg + reg;
      Kp[nt*1280 + tok*20 + lr] = f2bf(ka[nt][reg] + bkc);
      Qp[nt*1280 + tok*20 + lr] = f2bf((qa[nt][reg] + bqc) * 0.25f);
    }
    int tok0 = band + 4*lg;
    *(uint2*)(Vt + nt*1152 + lr*72 + tok0) =
        make_uint2(packf2(va[nt][0]+bvc, va[nt][1]+bvc),
                   packf2(va[nt][2]+bvc, va[nt][3]+bvc));
  }
  __syncthreads();

  // ---- windowed attention: wave = head; MFMA S^T = K*Q^T (slot-paired K_eff=16) ----
  {
    frag_u kaf[4], qbf[4], vbf[4], pf;
    #pragma unroll
    for (int tt = 0; tt < 4; ++tt) {
      kaf[tt].u2[0] = *(const uint2*)(Kp + w*1280 + (tt*16+lr)*20 + lg*4);
      kaf[tt].u[2] = 0; kaf[tt].u[3] = 0;
      qbf[tt].u2[0] = *(const uint2*)(Qp + w*1280 + (tt*16+lr)*20 + lg*4);
      qbf[tt].u[2] = 0; qbf[tt].u[3] = 0;
      vbf[tt].u2[0] = *(const uint2*)(Vt + w*1152 + lr*72 + tt*16 + lg*4);
      vbf[tt].u[2] = 0; vbf[tt].u[3] = 0;
    }
    f32x4 st[4][4];
    #pragma unroll
    for (int kt = 0; kt < 4; ++kt)
      #pragma unroll
      for (int qt = 0; qt < 4; ++qt) {
        f32x4 z = zf4();
        st[kt][qt] = MFMA16(kaf[kt].v, qbf[qt].v, z);
      }
    f32x4 oacc[4];
    #pragma unroll
    for (int qt = 0; qt < 4; ++qt) {
      float M = -1e30f;
      #pragma unroll
      for (int kt = 0; kt < 4; ++kt)
        #pragma unroll
        for (int reg = 0; reg < 4; ++reg) M = fmaxf(M, st[kt][qt][reg]);
      M = fmaxf(M, __shfl_xor(M, 16));
      M = fmaxf(M, __shfl_xor(M, 32));
      float s = 0.f;
      #pragma unroll
      for (int kt = 0; kt < 4; ++kt)
        #pragma unroll
        for (int reg = 0; reg < 4; ++reg) {
          float e = __expf(st[kt][qt][reg] - M);
          st[kt][qt][reg] = e; s += e;
        }
      s += __shfl_xor(s, 16);
      s += __shfl_xor(s, 32);
      if (lg == 0) sums[w*64 + qt*16 + lr] = s;
      oacc[qt] = zf4();
    }
    #pragma unroll
    for (int qt = 0; qt < 4; ++qt)
      #pragma unroll
      for (int kt = 0; kt < 4; ++kt) {
        pf.u[0] = packf2(st[kt][qt][0], st[kt][qt][1]);
        pf.u[1] = packf2(st[kt][qt][2], st[kt][qt][3]);
        pf.u[2] = 0; pf.u[3] = 0;
        oacc[qt] = MFMA16(pf.v, vbf[kt].v, oacc[qt]);
      }
    __syncthreads();
    #pragma unroll
    for (int qt = 0; qt < 4; ++qt)
      #pragma unroll
      for (int reg = 0; reg < 4; ++reg) {
        int q = qt*16 + 4*lg + reg;
        OB[q*72 + band + lr] = f2bf(oacc[qt][reg] / sums[w*64 + q]);
      }
  }
  __syncthreads();

  // ---- O@Wo + bo + agent + residual(h bf16) + lepe -> LN1 ----
  float comb[4][4];
  {
    f32x4 wa[4];
    #pragma unroll
    for (int nt = 0; nt < 4; ++nt) wa[nt] = zf4();
    #pragma unroll
    for (int ks = 0; ks < 2; ++ks) {
      bf16x8 a = ldfrag(OB + (band + lr)*72 + ks*32 + lg*8);
      #pragma unroll
      for (int nt = 0; nt < 4; ++nt)
        wa[nt] = MFMA16(a, ldfrag(wB + 16384 + ((ks*4+nt)*64 + l)*8), wa[nt]);
    }
    #pragma unroll
    for (int nt = 0; nt < 4; ++nt) {
      int col = nt*16 + lr;
      float cadd = bo[col] + agvs[col] + getvb[col];
      #pragma unroll
      for (int reg = 0; reg < 4; ++reg) {
        int row = band + lg*4 + reg;
        comb[nt][reg] = wa[nt][reg] + la[nt][reg] + cadd + bf2f(HsB[row*72 + col]);
      }
    }
  }
  {
    float mean1[4], rstd1[4];
    #pragma unroll
    for (int reg = 0; reg < 4; ++reg) {
      float s = comb[0][reg]+comb[1][reg]+comb[2][reg]+comb[3][reg];
      float qq = comb[0][reg]*comb[0][reg]+comb[1][reg]*comb[1][reg]
               + comb[2][reg]*comb[2][reg]+comb[3][reg]*comb[3][reg];
      s += __shfl_xor(s,1); qq += __shfl_xor(qq,1);
      s += __shfl_xor(s,2); qq += __shfl_xor(qq,2);
      s += __shfl_xor(s,4); qq += __shfl_xor(qq,4);
      s += __shfl_xor(s,8); qq += __shfl_xor(qq,8);
      float mn = s*0.015625f;
      mean1[reg] = mn;
      rstd1[reg] = rsqrtf(qq*0.015625f - mn*mn + 1e-5f);
    }
    #pragma unroll
    for (int nt = 0; nt < 4; ++nt) {
      int col = nt*16 + lr;
      float gg = g1[col], bb = be1[col];
      #pragma unroll
      for (int reg = 0; reg < 4; ++reg) {
        int row = band + lg*4 + reg;
        float h1 = (comb[nt][reg]-mean1[reg])*rstd1[reg]*gg + bb;
        HsB[row*72 + col] = f2bf(h1);
      }
    }
  }
  __syncthreads();

  // ---- FFN1: h1 @ W1 (64->128) + relu -> HidB ----
  {
    f32x4 fa[8];
    #pragma unroll
    for (int nt = 0; nt < 8; ++nt) fa[nt] = zf4();
    #pragma unroll
    for (int ks = 0; ks < 2; ++ks) {
      bf16x8 a = ldfrag(HsB + (band + lr)*72 + ks*32 + lg*8);
      #pragma unroll
      for (int nt = 0; nt < 8; ++nt)
        fa[nt] = MFMA16(a, ldfrag(wB + 20480 + ((ks*8+nt)*64 + l)*8), fa[nt]);
    }
    #pragma unroll
    for (int nt = 0; nt < 8; ++nt) {
      int col = nt*16 + lr;
      float b1c = b1[col];
      #pragma unroll
      for (int reg = 0; reg < 4; ++reg) {
        int row = band + lg*4 + reg;
        HidB[row*136 + col] = f2bf(fmaxf(fa[nt][reg] + b1c, 0.f));
      }
    }
  }
  __syncthreads();

  // ---- FFN2 + residual(h1 bf16) -> LN2 -> out (+pool partials) ----
  {
    f32x4 f2[4];
    #pragma unroll
    for (int nt = 0; nt < 4; ++nt) f2[nt] = zf4();
    #pragma unroll
    for (int ks = 0; ks < 4; ++ks) {
      bf16x8 a = ldfrag(HidB + (band + lr)*136 + ks*32 + lg*8);
      #pragma unroll
      for (int nt = 0; nt < 4; ++nt)
        f2[nt] = MFMA16(a, ldfrag(wB + 28672 + ((ks*4+nt)*64 + l)*8), f2[nt]);
    }
    float c2[4][4];
    #pragma unroll
    for (int nt = 0; nt < 4; ++nt) {
      int col = nt*16 + lr;
      float b2c = b2[col];
      #pragma unroll
      for (int reg = 0; reg < 4; ++reg) {
        int row = band + lg*4 + reg;
        c2[nt][reg] = f2[nt][reg] + b2c + bf2f(HsB[row*72 + col]);
      }
    }
    float mean2[4], rstd2[4];
    #pragma unroll
    for (int reg = 0; reg < 4; ++reg) {
      float s = c2[0][reg]+c2[1][reg]+c2[2][reg]+c2[3][reg];
      float qq = c2[0][reg]*c2[0][reg]+c2[1][reg]*c2[1][reg]
               + c2[2][reg]*c2[2][reg]+c2[3][reg]*c2[3][reg];
      s += __shfl_xor(s,1); qq += __shfl_xor(qq,1);
      s += __shfl_xor(s,2); qq += __shfl_xor(qq,2);
      s += __shfl_xor(s,4); qq += __shfl_xor(qq,4);
      s += __shfl_xor(s,8); qq += __shfl_xor(qq,8);
      float mn = s*0.015625f;
      mean2[reg] = mn;
      rstd2[reg] = rsqrtf(qq*0.015625f - mn*mn + 1e-5f);
    }
    __syncthreads();
    #pragma unroll
    for (int nt = 0; nt < 4; ++nt) {
      int col = nt*16 + lr;
      float gg = g2[col], bb = be2[col];
      float part = 0.f;
      #pragma unroll
      for (int reg = 0; reg < 4; ++reg) {
        int row = band + lg*4 + reg;
        float y = (c2[nt][reg]-mean2[reg])*rstd2[reg]*gg + bb;
        if (OUT_BF16) Y16[(n0 + row)*64 + col] = f2bf(y);
        else          Y[(n0 + row)*64 + col] = y;
        part += y;
      }
      red[col*17 + w*4 + lg] = part;
    }
  }
  __syncthreads();
  if (t < 64) {
    float s = 0.f;
    #pragma unroll
    for (int g = 0; g < 16; ++g) s += red[t*17 + g];
    pp[(size_t)blockIdx.x*64 + t] = s;
  }
}

extern "C" void kernel_launch(void* const* d_in, const int* in_sizes, int n_in,
                              void* d_out, int out_size, void* d_ws, size_t ws_size,
                              hipStream_t stream) {
  (void)in_sizes; (void)n_in; (void)out_size; (void)ws_size;
  const float* x    = (const float*)d_in[0];
  const float* dck  = (const float*)d_in[1];
  const float* dcw1 = (const float*)d_in[2];
  const float* dcb1 = (const float*)d_in[3];
  const float* dcw2 = (const float*)d_in[4];
  const float* dcb2 = (const float*)d_in[5];
  const float* embw = (const float*)d_in[6];
  const float* embb = (const float*)d_in[7];
  const float* getvw= (const float*)d_in[8];
  const float* getvb= (const float*)d_in[9];
  const float* anb  = (const float*)d_in[10];
  // d_in[11] = na_bias: provably unused (softmax over size-1 axis == 1)
  const float* wq = (const float*)d_in[12]; const float* bq = (const float*)d_in[13];
  const float* wk = (const float*)d_in[14]; const float* bk = (const float*)d_in[15];
  const float* wv = (const float*)d_in[16]; const float* bv = (const float*)d_in[17];
  const float* wo = (const float*)d_in[18]; const float* bo = (const float*)d_in[19];
  const float* fw1= (const float*)d_in[20]; const float* fb1= (const float*)d_in[21];
  const float* fw2= (const float*)d_in[22]; const float* fb2= (const float*)d_in[23];
  const float* g1 = (const float*)d_in[24]; const float* be1= (const float*)d_in[25];
  const float* g2 = (const float*)d_in[26]; const float* be2= (const float*)d_in[27];

  float* out = (float*)d_out;
  float* ws  = (float*)d_ws;
  float* pp    = ws;                    // [16][64][64] (also 16-chunk pool for x)
  float* pm    = pp + 65536;            // [16][16][8]
  float* pe    = pm + 2048;
  float* pw    = pe + 2048;             // [16][16][8][64]
  float* attns = pw + 131072;           // [16][3][3] (pad 256)
  ushort* hB0  = (ushort*)(attns + 256);          // bf16 h buffers (8.4 MB each)
  ushort* hB1  = hB0 + (size_t)BB*LL*64;
  ushort* weffB= hB1 + (size_t)BB*LL*64;          // [3][16][12288]
  ushort* wsB  = weffB + (size_t)3*BB*12288;      // 3 x 36864
  ushort* wsE  = wsB + (size_t)3*36864;           // 4096

  dim3 blk(256);
  const int NT = BB*LL/64;  // 1024 row-tiles

  k_pack<<<dim3(160, 3), blk, 0, stream>>>(wq, wk, wv, getvw, wo, fw1, fw2, embw, wsB, wsE);
  k_pool_part<<<dim3(BB,16), blk, 0, stream>>>(x, pp);
  k_attns<<<BB, blk, 0, stream>>>(pp, x, dcw1, dcb1, dcw2, dcb2, dck, attns);
  k_wefff<<<dim3(BB,24), blk, 0, stream>>>(attns, dck, weffB);
  k_convF<<<dim3(BB,64), blk, 0, stream>>>(x, weffB, wsE, embb, hB0, pp);

  ushort* h  = hB0;
  ushort* hn = hB1;
  for (int i = 0; i < 3; ++i) {
    k_agent2<<<dim3(BB,16), blk, 0, stream>>>(h, anb + (size_t)i*8*4096, pp, pm, pe, pw);
    if (i == 2) {
      k_layer<false><<<NT, blk, 0, stream>>>(h, pm, pe, pw, getvw + i*4096, getvb + i*64,
                                             wsB + (size_t)i*36864,
                                             bq + i*64, bk + i*64, bv + i*64, bo + i*64,
                                             g1 + i*64, be1 + i*64, fb1 + i*128, fb2 + i*64,
                                             g2 + i*64, be2 + i*64, out, nullptr, pp);
    } else {
      k_layer<true><<<NT, blk, 0, stream>>>(h, pm, pe, pw, getvw + i*4096, getvb + i*64,
                                            wsB + (size_t)i*36864,
                                            bq + i*64, bk + i*64, bv + i*64, bo + i*64,
                                            g1 + i*64, be1 + i*64, fb1 + i*128, fb2 + i*64,
                                            g2 + i*64, be2 + i*64, nullptr, hn, pp);
    }
    ushort* tmp = h; h = hn; hn = tmp;
  }
}

// Round 11
// 190.622 us; speedup vs baseline: 1.1075x; 1.1075x over previous
//
#include <hip/hip_runtime.h>

#define BB 16
#define LL 4096
#define DD 64

typedef const float* __restrict__ cfp;
typedef float* __restrict__ fp;
typedef const ushort* __restrict__ cup;
typedef ushort* __restrict__ up;

typedef __attribute__((ext_vector_type(8))) short bf16x8;
typedef __attribute__((ext_vector_type(4))) float f32x4;
#define MFMA16(a, b, c) __builtin_amdgcn_mfma_f32_16x16x32_bf16(a, b, c, 0, 0, 0)

__device__ __forceinline__ f32x4 zf4(){ f32x4 z; z[0]=0.f; z[1]=0.f; z[2]=0.f; z[3]=0.f; return z; }

union frag_u { bf16x8 v; uint2 u2[2]; uint u[4]; };

__device__ __forceinline__ float4 ld4(const float* p){ return *reinterpret_cast<const float4*>(p); }

__device__ __forceinline__ ushort f2bf(float f){
  uint u = __float_as_uint(f);
  return (ushort)((u + 0x7FFFu + ((u >> 16) & 1u)) >> 16);   // RNE
}
__device__ __forceinline__ float bf2f(ushort u){
  return __uint_as_float(((uint)u) << 16);
}
__device__ __forceinline__ uint packf2(float a, float b){
  return (uint)f2bf(a) | ((uint)f2bf(b) << 16);
}
__device__ __forceinline__ uint2 pack4(float4 v){
  return make_uint2(packf2(v.x, v.y), packf2(v.z, v.w));
}
__device__ __forceinline__ bf16x8 ldfrag(const ushort* p){ return *reinterpret_cast<const bf16x8*>(p); }

// ---------------- weight packing into bf16 B-fragments (+ emb) ----------------
__global__ __launch_bounds__(256) void k_pack(cfp wq, cfp wk, cfp wv, cfp getv, cfp wo,
                                              cfp fw1, cfp fw2, cfp embw,
                                              up dst, up dstE) {
  int layer = blockIdx.y;
  int e = blockIdx.x*256 + threadIdx.x;        // e < 40960
  if (e >= 36864) {
    int rem = e - 36864;
    int j = rem & 7, lane = (rem >> 3) & 63, rest = rem >> 9;
    int nt = rest & 3, ks = rest >> 2;
    int k = ks*32 + ((lane >> 4) << 3) + j, n = nt*16 + (lane & 15);
    dstE[rem] = f2bf(embw[k*64 + n]);
    return;
  }
  const float* W; int N, rem;
  if (e < 20480) {
    int mm = e >> 12; rem = e & 4095;
    W = (mm==0?wq: mm==1?wk: mm==2?wv: mm==3?getv: wo) + layer*4096; N = 64;
  } else if (e < 28672) {
    rem = e - 20480; W = fw1 + layer*8192; N = 128;
  } else {
    rem = e - 28672; W = fw2 + layer*8192; N = 64;
  }
  int NT = N >> 4;
  int j = rem & 7, lane = (rem >> 3) & 63, rest = rem >> 9;
  int nt = rest % NT, ks = rest / NT;
  int k = ks*32 + ((lane >> 4) << 3) + j, n = nt*16 + (lane & 15);
  dst[(size_t)layer*36864 + e] = f2bf(W[(size_t)k*N + n]);
}

// ---------------- pooling of raw input x (16 chunks) ----------------
__global__ __launch_bounds__(256) void k_pool_part(cfp h, fp pp) {
  int b = blockIdx.x, gblk = blockIdx.y, t = threadIdx.x;
  int c = t & 63, r = t >> 6;
  const float* base = h + ((size_t)b*LL + (size_t)gblk*256)*64;
  float acc = 0.f;
  for (int l = r; l < 256; l += 4) acc += base[(size_t)l*64 + c];
  __shared__ float red[4][64];
  red[r][c] = acc; __syncthreads();
  if (t < 64) pp[(b*16 + gblk)*64 + t] = red[0][t]+red[1][t]+red[2][t]+red[3][t];
}

// ---------------- tiny MLP (pooled -> 3-way softmax attn), block-uniform ----------------
__device__ __forceinline__ void tiny_mlp3(int t, const float* __restrict__ pooled,
                                          cfp w1, cfp b1, cfp w2, cfp b2,
                                          float* attn, float* hdn) {
  if (t < 16) {
    float a = b1[t];
    for (int c = 0; c < 64; ++c) a += pooled[c]*w1[t*64 + c];
    hdn[t] = fmaxf(a, 0.f);
  }
  __syncthreads();
  if (t < 3) {
    float a = b2[t];
    for (int j = 0; j < 16; ++j) a += hdn[j]*w2[t*16 + j];
    attn[t] = a;
  }
  __syncthreads();
  if (t == 0) {
    float m = fmaxf(attn[0], fmaxf(attn[1], attn[2]));
    float e0 = __expf(attn[0]-m), e1 = __expf(attn[1]-m), e2 = __expf(attn[2]-m);
    float s = e0+e1+e2;
    attn[0]=e0/s; attn[1]=e1/s; attn[2]=e2/s;
  }
  __syncthreads();
}

// ---------------- parallel precompute, stage 0: R0[b][type][k][64] ----------------
// type 0: Sigma-recursion vector; type 1: first-row vector; type 2: last-row vector.
__global__ __launch_bounds__(256) void k_prep0(cfp pp, cfp x, cfp dck, fp R0) {
  int b = blockIdx.x, k = blockIdx.y, t = threadIdx.x;
  __shared__ float S[64], e0v[64], e1v[64], em0[64], em1[64];
  __shared__ float redu[3][256];
  const float* xb = x + (size_t)b*LL*64;
  if (t < 64) {
    float s = 0.f;
    for (int g = 0; g < 16; ++g) s += pp[((size_t)b*16 + g)*64 + t];
    S[t] = s;
    e0v[t] = xb[t]; e1v[t] = xb[64 + t];
    em0[t] = xb[(size_t)(LL-2)*64 + t]; em1[t] = xb[(size_t)(LL-1)*64 + t];
  }
  __syncthreads();
  int co = t & 63, q = t >> 6;
  cfp kb = dck + (size_t)k*36864;
  float pS = 0.f, ph0 = 0.f, phm = 0.f;
  for (int ci = q*16; ci < q*16 + 16; ++ci) {
    size_t base = ((size_t)co*64 + ci)*9 + 1;
    float w0 = kb[base], w1 = kb[base+3], w2 = kb[base+6];
    pS  += w0*(S[ci]-em1[ci]) + w1*S[ci] + w2*(S[ci]-e0v[ci]);
    ph0 += w1*e0v[ci] + w2*e1v[ci];
    phm += w0*em0[ci] + w1*em1[ci];
  }
  redu[0][t] = pS; redu[1][t] = ph0; redu[2][t] = phm;
  __syncthreads();
  if (t < 64) {
    R0[((b*3 + 0)*3 + k)*64 + t] = redu[0][t]+redu[0][64+t]+redu[0][128+t]+redu[0][192+t];
    R0[((b*3 + 1)*3 + k)*64 + t] = redu[1][t]+redu[1][64+t]+redu[1][128+t]+redu[1][192+t];
    R0[((b*3 + 2)*3 + k)*64 + t] = redu[2][t]+redu[2][64+t]+redu[2][128+t]+redu[2][192+t];
  }
}

// ---------------- parallel precompute, stage 1: T1[b][k*3+k0][64] ----------------
__global__ __launch_bounds__(256) void k_prep1(cfp R0, cfp dck, fp T1) {
  int b = blockIdx.x, k = blockIdx.y / 3, k0 = blockIdx.y % 3, t = threadIdx.x;
  __shared__ float u0[64], u1[64], u2[64];
  __shared__ float redu[256];
  if (t < 64) {
    float rs  = R0[((b*3 + 0)*3 + k0)*64 + t];
    float rh0 = R0[((b*3 + 1)*3 + k0)*64 + t];
    float rhm = R0[((b*3 + 2)*3 + k0)*64 + t];
    u0[t] = rs - rhm; u1[t] = rs; u2[t] = rs - rh0;
  }
  __syncthreads();
  int co = t & 63, q = t >> 6;
  cfp kb = dck + 110592 + (size_t)k*36864;
  float pS = 0.f;
  for (int ci = q*16; ci < q*16 + 16; ++ci) {
    size_t base = ((size_t)co*64 + ci)*9 + 1;
    pS += kb[base]*u0[ci] + kb[base+3]*u1[ci] + kb[base+6]*u2[ci];
  }
  redu[t] = pS;
  __syncthreads();
  if (t < 64)
    T1[((size_t)b*9 + blockIdx.y)*64 + t] = redu[t]+redu[64+t]+redu[128+t]+redu[192+t];
}

// ---------------- tiny serial chain: 3 MLPs over precomputed reductions ----------------
__global__ __launch_bounds__(256) void k_attns2(cfp pp, cfp R0, cfp T1,
                                                cfp dcw1, cfp dcb1, cfp dcw2, cfp dcb2,
                                                fp attns) {
  int b = blockIdx.x, t = threadIdx.x;
  __shared__ float pooled[64], hdn[16], attn[3], a0s[3], a1s[3];
  if (t < 64) {
    float s = 0.f;
    for (int g = 0; g < 16; ++g) s += pp[((size_t)b*16 + g)*64 + t];
    pooled[t] = s * (1.f/4096.f);
  }
  __syncthreads();
  tiny_mlp3(t, pooled, dcw1, dcb1, dcw2, dcb2, attn, hdn);
  if (t < 3) { attns[b*9 + t] = attn[t]; a0s[t] = attn[t]; }
  __syncthreads();
  if (t < 64) {
    float sn = a0s[0]*R0[((b*3+0)*3 + 0)*64 + t]
             + a0s[1]*R0[((b*3+0)*3 + 1)*64 + t]
             + a0s[2]*R0[((b*3+0)*3 + 2)*64 + t];
    pooled[t] = sn * (1.f/4096.f);
  }
  __syncthreads();
  tiny_mlp3(t, pooled, dcw1+1024, dcb1+16, dcw2+48, dcb2+3, attn, hdn);
  if (t < 3) { attns[b*9 + 3 + t] = attn[t]; a1s[t] = attn[t]; }
  __syncthreads();
  if (t < 64) {
    float s2 = 0.f;
    #pragma unroll
    for (int k = 0; k < 3; ++k)
      #pragma unroll
      for (int k0 = 0; k0 < 3; ++k0)
        s2 += a1s[k]*a0s[k0]*T1[((size_t)b*9 + k*3 + k0)*64 + t];
    pooled[t] = s2 * (1.f/4096.f);
  }
  __syncthreads();
  tiny_mlp3(t, pooled, dcw1+2048, dcb1+32, dcw2+96, dcb2+6, attn, hdn);
  if (t < 3) attns[b*9 + 6 + t] = attn[t];
}

// ---------------- effective-kernel fragment writer (all 3 stages) ----------------
__global__ __launch_bounds__(256) void k_wefff(cfp attns, cfp dck, up weffB) {
  int b = blockIdx.x, stage = blockIdx.y >> 3, slice = blockIdx.y & 7, t = threadIdx.x;
  float a0 = attns[b*9 + stage*3 + 0];
  float a1 = attns[b*9 + stage*3 + 1];
  float a2 = attns[b*9 + stage*3 + 2];
  cfp kern = dck + (size_t)stage*110592;
  int e0i = slice*1536;
  for (int e = e0i + t; e < e0i + 1536; e += 256) {
    int j = e & 7, lane = (e >> 3) & 63, nt = (e >> 9) & 3, ks = e >> 11;
    int k = ks*32 + ((lane >> 4) << 3) + j;
    int co = nt*16 + (lane & 15);
    int kh = k >> 6, ci = k & 63;
    size_t base = ((size_t)co*64 + ci)*9 + kh*3 + 1;     // kw=1 only (W=1 with pad)
    float v = a0*kern[base] + a1*kern[base + 36864] + a2*kern[base + 2*36864];
    weffB[((size_t)stage*16 + b)*12288 + e] = f2bf(v);
  }
}

// ---------------- conv MFMA core ----------------
__device__ __forceinline__ void conv_mfma(const ushort* Ts, const ushort* wb,
                                          int band, int lr, int lg, int l, f32x4 acc[4]) {
  #pragma unroll
  for (int nt = 0; nt < 4; ++nt) acc[nt] = zf4();
  #pragma unroll
  for (int ks = 0; ks < 6; ++ks) {
    int k8 = ks*32 + lg*8;
    int kh = k8 >> 6, ci = k8 & 63;
    bf16x8 a = ldfrag(Ts + (band + lr + kh)*72 + ci);
    #pragma unroll
    for (int nt = 0; nt < 4; ++nt)
      acc[nt] = MFMA16(a, ldfrag(wb + ((ks*4+nt)*64 + l)*8), acc[nt]);
  }
}

// ---------------- fused conv stem: 3 dynamic-conv stages + emb GEMM, halo'd ----------------
__global__ __launch_bounds__(256) void k_convF(cfp x, cup weffB, cup wE, cfp embb,
                                               up houtB, fp pp) {
  int b = blockIdx.x, wblk = blockIdx.y, t = threadIdx.x;
  int n0 = wblk*64;
  __shared__ ushort TsA[84*72];
  __shared__ ushort TsB[84*72];
  __shared__ float red[64*17];
  int w = t >> 6, l = t & 63, lr = l & 15, lg = l >> 4;

  for (int idx = t; idx < 1344; idx += 256) {
    int r = idx >> 4, c4 = (idx & 15)*4;
    int g = n0 - 4 + r;
    float4 v = make_float4(0.f,0.f,0.f,0.f);
    if (r >= 1 && r <= 70 && g >= 0 && g < LL) v = ld4(x + ((size_t)b*LL + g)*64 + c4);
    *(uint2*)(TsA + r*72 + c4) = pack4(v);
  }
  for (int idx = t; idx < 32; idx += 256) {       // zero TsB guard rows 82,83
    int r = 82 + (idx >> 4), c4 = (idx & 15)*4;
    *(uint2*)(TsB + r*72 + c4) = make_uint2(0u,0u);
  }
  __syncthreads();

  // ---- stage 0: TsA -> TsB (zero-force rows outside [0,LL)) ----
  {
    const ushort* wb = weffB + (size_t)b*12288;
    for (int bi = w; bi < 5; bi += 4) {
      int band = 2 + bi*16;
      f32x4 acc[4];
      conv_mfma(TsA, wb, band - 1, lr, lg, l, acc);
      #pragma unroll
      for (int nt = 0; nt < 4; ++nt)
        #pragma unroll
        for (int reg = 0; reg < 4; ++reg) {
          int row = band + lg*4 + reg;
          int g = n0 - 4 + row;
          float v = (g >= 0 && g < LL) ? acc[nt][reg] : 0.f;
          TsB[row*72 + nt*16 + lr] = f2bf(v);
        }
    }
  }
  __syncthreads();
  // ---- stage 1: TsB -> TsA (zero-force rows outside [0,LL)) ----
  {
    const ushort* wb = weffB + (size_t)(16 + b)*12288;
    for (int bi = w; bi < 5; bi += 4) {
      int band = 3 + bi*16;
      f32x4 acc[4];
      conv_mfma(TsB, wb, band - 1, lr, lg, l, acc);
      #pragma unroll
      for (int nt = 0; nt < 4; ++nt)
        #pragma unroll
        for (int reg = 0; reg < 4; ++reg) {
          int row = band + lg*4 + reg;
          int g = n0 - 4 + row;
          float v = (g >= 0 && g < LL) ? acc[nt][reg] : 0.f;
          TsA[row*72 + nt*16 + lr] = f2bf(v);
        }
    }
  }
  __syncthreads();
  // ---- stage 2: TsA -> TsB (exactly 4 bands, all in-range) ----
  {
    const ushort* wb = weffB + (size_t)(32 + b)*12288;
    int band = 4 + w*16;
    f32x4 acc[4];
    conv_mfma(TsA, wb, band - 1, lr, lg, l, acc);
    #pragma unroll
    for (int nt = 0; nt < 4; ++nt)
      #pragma unroll
      for (int reg = 0; reg < 4; ++reg)
        TsB[(band + lg*4 + reg)*72 + nt*16 + lr] = f2bf(acc[nt][reg]);
  }
  __syncthreads();
  // ---- emb GEMM on stage-2 rows; bounce via TsA for coalesced store ----
  {
    int band = 4 + w*16;
    f32x4 ea[4];
    #pragma unroll
    for (int nt = 0; nt < 4; ++nt) ea[nt] = zf4();
    #pragma unroll
    for (int ks = 0; ks < 2; ++ks) {
      bf16x8 a = ldfrag(TsB + (band + lr)*72 + ks*32 + lg*8);
      #pragma unroll
      for (int nt = 0; nt < 4; ++nt)
        ea[nt] = MFMA16(a, ldfrag(wE + ((ks*4+nt)*64 + l)*8), ea[nt]);
    }
    #pragma unroll
    for (int nt = 0; nt < 4; ++nt) {
      int col = nt*16 + lr;
      float bc = embb[col], part = 0.f;
      #pragma unroll
      for (int reg = 0; reg < 4; ++reg) {
        int row = band + lg*4 + reg;
        float y = ea[nt][reg] + bc;
        TsA[row*72 + col] = f2bf(y);
        part += y;
      }
      red[col*17 + w*4 + lg] = part;
    }
  }
  __syncthreads();
  for (int idx = t; idx < 512; idx += 256) {
    int r = idx >> 3, c8 = (idx & 7)*8;
    *(uint4*)(houtB + ((size_t)b*LL + n0 + r)*64 + c8) = *(const uint4*)(TsA + (r+4)*72 + c8);
  }
  if (t < 64) {
    float s = 0.f;
    #pragma unroll
    for (int g = 0; g < 16; ++g) s += red[t*17 + g];
    pp[((size_t)b*64 + wblk)*64 + t] = s;
  }
}

// ---------------- agent attention: chunked scores + weighted-sum partials (bf16 h) ----------------
__global__ __launch_bounds__(256) void k_agent2(cup h16, cfp anb, cfp pp,
                                                fp pm, fp pe, fp pw) {
  int b = blockIdx.x, ch = blockIdx.y, t = threadIdx.x;
  int w = t >> 6, l = t & 63;
  __shared__ float means_s[64];
  __shared__ float sc[8][258];
  __shared__ float red4[4][64];
  __shared__ float esp[8][33];
  __shared__ float mcs[8], ess[8];
  __shared__ float wred[4][8][64];
  {
    float acc = 0.f;
    for (int c = w; c < 64; c += 4) acc += pp[((size_t)b*64 + c)*64 + l];
    red4[w][l] = acc;
  }
  __syncthreads();
  if (t < 64) means_s[t] = (red4[0][t]+red4[1][t]+red4[2][t]+red4[3][t])
                           * (1.f/4096.f) * 0.35355339059327373f;
  __syncthreads();
  const ushort* hb = h16 + ((size_t)b*LL + (size_t)ch*256)*64;
  int g8 = l >> 3, k8 = l & 7;
  float ms8[8];
  #pragma unroll
  for (int j = 0; j < 8; ++j) ms8[j] = means_s[k8*8 + j];
  #pragma unroll
  for (int it = 0; it < 8; ++it) {
    int n = w*64 + it*8 + g8;
    uint4 hv = *(const uint4*)(hb + (size_t)n*64 + k8*8);
    float d = bf2f((ushort)(hv.x & 0xffffu))*ms8[0] + bf2f((ushort)(hv.x >> 16))*ms8[1]
            + bf2f((ushort)(hv.y & 0xffffu))*ms8[2] + bf2f((ushort)(hv.y >> 16))*ms8[3]
            + bf2f((ushort)(hv.z & 0xffffu))*ms8[4] + bf2f((ushort)(hv.z >> 16))*ms8[5]
            + bf2f((ushort)(hv.w & 0xffffu))*ms8[6] + bf2f((ushort)(hv.w >> 16))*ms8[7];
    sc[k8][n] = d;
  }
  __syncthreads();
  int hh = t >> 5, j0 = (t & 31) * 8;
  const float* ab = anb + (size_t)hh*LL + ch*256 + j0;
  float loc[8];
  float mx = -1e30f;
  #pragma unroll
  for (int k = 0; k < 8; ++k) {
    loc[k] = sc[hh][j0 + k] + ab[k];
    mx = fmaxf(mx, loc[k]);
  }
  esp[hh][t & 31] = mx;
  __syncthreads();
  if (t < 8) {
    float m = -1e30f;
    for (int k = 0; k < 32; ++k) m = fmaxf(m, esp[t][k]);
    mcs[t] = m;
  }
  __syncthreads();
  {
    float M = mcs[hh], s = 0.f;
    #pragma unroll
    for (int k = 0; k < 8; ++k) {
      float e = __expf(loc[k] - M);
      sc[hh][j0 + k] = e;
      s += e;
    }
    esp[hh][t & 31] = s;
  }
  __syncthreads();
  if (t < 8) {
    float s = 0.f;
    for (int k = 0; k < 32; ++k) s += esp[t][k];
    ess[t] = s;
  }
  float acc8[8] = {};
  for (int i = 0; i < 64; ++i) {
    int n = w*64 + i;
    float xv = bf2f(hb[(size_t)n*64 + l]);
    #pragma unroll
    for (int q = 0; q < 8; ++q) acc8[q] = fmaf(sc[q][n], xv, acc8[q]);
  }
  __syncthreads();
  #pragma unroll
  for (int q = 0; q < 8; ++q) wred[w][q][l] = acc8[q];
  __syncthreads();
  for (int o = t; o < 512; o += 256) {
    int q = o >> 6, ll = o & 63;
    pw[(((size_t)b*16 + ch)*8 + q)*64 + ll] =
        wred[0][q][ll]+wred[1][q][ll]+wred[2][q][ll]+wred[3][q][ll];
  }
  if (t < 8) {
    pe[((size_t)b*16 + ch)*8 + t] = ess[t];
    pm[((size_t)b*16 + ch)*8 + t] = mcs[t];
  }
}

// ================= fused layer kernel (all-MFMA, agfin folded, bf16 in; templated out) =================
template<bool OUT_BF16>
__global__ __launch_bounds__(256, 4) void k_layer(
    cup h16, cfp pm, cfp pe, cfp pw, cfp getv, cfp getvb, cup wB,
    cfp bq, cfp bk, cfp bv, cfp bo,
    cfp g1, cfp be1, cfp b1, cfp b2, cfp g2, cfp be2,
    fp Y, up Y16, fp pp) {
  __shared__ float smem[10048];
  ushort* HsB  = (ushort*)(smem);
  ushort* Qp   = (ushort*)(smem + 2304);
  ushort* Kp   = (ushort*)(smem + 4864);
  ushort* Vt   = (ushort*)(smem + 7424);
  float*  sums = smem + 9728;
  float*  agvs = smem + 9984;
  float*  wm   = smem + 7424;          // [8][65] alias Vt (prologue only)
  float*  msden= smem + 7944;          // 16 fl
  ushort* OB   = (ushort*)(smem + 7424);
  float*  red  = smem + 7424;
  ushort* HidB = (ushort*)(smem + 2304);

  int t = threadIdx.x;
  size_t n0 = (size_t)blockIdx.x*64;
  int b = (int)(n0 >> 12);
  int w = t >> 6, l = t & 63, band = w*16, lr = l & 15, lg = l >> 4;

  #pragma unroll
  for (int it = 0; it < 2; ++it) {
    int idx = it*256 + t, r = idx >> 3, c8 = (idx & 7)*8;
    *(uint4*)(HsB + r*72 + c8) = *(const uint4*)(h16 + (n0 + r)*64 + c8);
  }
  if (t < 8) {
    float M = -1e30f;
    for (int c = 0; c < 16; ++c) M = fmaxf(M, pm[((size_t)b*16+c)*8 + t]);
    float d = 0.f;
    for (int c = 0; c < 16; ++c)
      d += pe[((size_t)b*16+c)*8 + t] * __expf(pm[((size_t)b*16+c)*8 + t] - M);
    msden[t] = M; msden[8+t] = d;
  }
  __syncthreads();
  for (int o = t; o < 512; o += 256) {
    int q = o >> 6, l2 = o & 63;
    float M = msden[q], s = 0.f;
    for (int c = 0; c < 16; ++c)
      s += pw[(((size_t)b*16+c)*8 + q)*64 + l2] * __expf(pm[((size_t)b*16+c)*8 + q] - M);
    wm[q*65 + l2] = s / msden[8+q];
  }
  __syncthreads();
  if (t < 64) {
    int q = t >> 3;
    float a = getvb[t];
    for (int c = 0; c < 64; ++c) a = fmaf(wm[q*65 + c], getv[c*64 + t], a);
    agvs[t] = a;
  }
  __syncthreads();

  // ---- Q,K,V,lepe MFMA GEMMs ----
  f32x4 ka[4], va[4], qa[4], la[4];
  #pragma unroll
  for (int nt = 0; nt < 4; ++nt) {
    ka[nt] = zf4(); va[nt] = zf4(); qa[nt] = zf4(); la[nt] = zf4();
  }
  #pragma unroll
  for (int ks = 0; ks < 2; ++ks) {
    bf16x8 a = ldfrag(HsB + (band + lr)*72 + ks*32 + lg*8);
    #pragma unroll
    for (int nt = 0; nt < 4; ++nt) {
      int fo = ((ks*4 + nt)*64 + l)*8;
      qa[nt] = MFMA16(a, ldfrag(wB + fo),         qa[nt]);
      ka[nt] = MFMA16(a, ldfrag(wB + 4096 + fo),  ka[nt]);
      va[nt] = MFMA16(a, ldfrag(wB + 8192 + fo),  va[nt]);
      la[nt] = MFMA16(a, ldfrag(wB + 12288 + fo), la[nt]);
    }
  }
  #pragma unroll
  for (int nt = 0; nt < 4; ++nt) {
    int col = nt*16 + lr;
    float bkc = bk[col], bvc = bv[col], bqc = bq[col];
    #pragma unroll
    for (int reg = 0; reg < 4; ++reg) {
      int tok = band + 4*lg + reg;
      Kp[nt*1280 + tok*20 + lr] = f2bf(ka[nt][reg] + bkc);
      Qp[nt*1280 + tok*20 + lr] = f2bf((qa[nt][reg] + bqc) * 0.25f);
    }
    int tok0 = band + 4*lg;
    *(uint2*)(Vt + nt*1152 + lr*72 + tok0) =
        make_uint2(packf2(va[nt][0]+bvc, va[nt][1]+bvc),
                   packf2(va[nt][2]+bvc, va[nt][3]+bvc));
  }
  __syncthreads();

  // ---- windowed attention: wave = head; MFMA S^T = K*Q^T (slot-paired K_eff=16) ----
  {
    frag_u kaf[4], qbf[4], vbf[4], pf;
    #pragma unroll
    for (int tt = 0; tt < 4; ++tt) {
      kaf[tt].u2[0] = *(const uint2*)(Kp + w*1280 + (tt*16+lr)*20 + lg*4);
      kaf[tt].u[2] = 0; kaf[tt].u[3] = 0;
      qbf[tt].u2[0] = *(const uint2*)(Qp + w*1280 + (tt*16+lr)*20 + lg*4);
      qbf[tt].u[2] = 0; qbf[tt].u[3] = 0;
      vbf[tt].u2[0] = *(const uint2*)(Vt + w*1152 + lr*72 + tt*16 + lg*4);
      vbf[tt].u[2] = 0; vbf[tt].u[3] = 0;
    }
    f32x4 st[4][4];
    #pragma unroll
    for (int kt = 0; kt < 4; ++kt)
      #pragma unroll
      for (int qt = 0; qt < 4; ++qt) {
        f32x4 z = zf4();
        st[kt][qt] = MFMA16(kaf[kt].v, qbf[qt].v, z);
      }
    f32x4 oacc[4];
    #pragma unroll
    for (int qt = 0; qt < 4; ++qt) {
      float M = -1e30f;
      #pragma unroll
      for (int kt = 0; kt < 4; ++kt)
        #pragma unroll
        for (int reg = 0; reg < 4; ++reg) M = fmaxf(M, st[kt][qt][reg]);
      M = fmaxf(M, __shfl_xor(M, 16));
      M = fmaxf(M, __shfl_xor(M, 32));
      float s = 0.f;
      #pragma unroll
      for (int kt = 0; kt < 4; ++kt)
        #pragma unroll
        for (int reg = 0; reg < 4; ++reg) {
          float e = __expf(st[kt][qt][reg] - M);
          st[kt][qt][reg] = e; s += e;
        }
      s += __shfl_xor(s, 16);
      s += __shfl_xor(s, 32);
      if (lg == 0) sums[w*64 + qt*16 + lr] = s;
      oacc[qt] = zf4();
    }
    #pragma unroll
    for (int qt = 0; qt < 4; ++qt)
      #pragma unroll
      for (int kt = 0; kt < 4; ++kt) {
        pf.u[0] = packf2(st[kt][qt][0], st[kt][qt][1]);
        pf.u[1] = packf2(st[kt][qt][2], st[kt][qt][3]);
        pf.u[2] = 0; pf.u[3] = 0;
        oacc[qt] = MFMA16(pf.v, vbf[kt].v, oacc[qt]);
      }
    __syncthreads();
    #pragma unroll
    for (int qt = 0; qt < 4; ++qt)
      #pragma unroll
      for (int reg = 0; reg < 4; ++reg) {
        int q = qt*16 + 4*lg + reg;
        OB[q*72 + band + lr] = f2bf(oacc[qt][reg] / sums[w*64 + q]);
      }
  }
  __syncthreads();

  // ---- O@Wo + bo + agent + residual(h bf16) + lepe -> LN1 ----
  float comb[4][4];
  {
    f32x4 wa[4];
    #pragma unroll
    for (int nt = 0; nt < 4; ++nt) wa[nt] = zf4();
    #pragma unroll
    for (int ks = 0; ks < 2; ++ks) {
      bf16x8 a = ldfrag(OB + (band + lr)*72 + ks*32 + lg*8);
      #pragma unroll
      for (int nt = 0; nt < 4; ++nt)
        wa[nt] = MFMA16(a, ldfrag(wB + 16384 + ((ks*4+nt)*64 + l)*8), wa[nt]);
    }
    #pragma unroll
    for (int nt = 0; nt < 4; ++nt) {
      int col = nt*16 + lr;
      float cadd = bo[col] + agvs[col] + getvb[col];
      #pragma unroll
      for (int reg = 0; reg < 4; ++reg) {
        int row = band + lg*4 + reg;
        comb[nt][reg] = wa[nt][reg] + la[nt][reg] + cadd + bf2f(HsB[row*72 + col]);
      }
    }
  }
  {
    float mean1[4], rstd1[4];
    #pragma unroll
    for (int reg = 0; reg < 4; ++reg) {
      float s = comb[0][reg]+comb[1][reg]+comb[2][reg]+comb[3][reg];
      float qq = comb[0][reg]*comb[0][reg]+comb[1][reg]*comb[1][reg]
               + comb[2][reg]*comb[2][reg]+comb[3][reg]*comb[3][reg];
      s += __shfl_xor(s,1); qq += __shfl_xor(qq,1);
      s += __shfl_xor(s,2); qq += __shfl_xor(qq,2);
      s += __shfl_xor(s,4); qq += __shfl_xor(qq,4);
      s += __shfl_xor(s,8); qq += __shfl_xor(qq,8);
      float mn = s*0.015625f;
      mean1[reg] = mn;
      rstd1[reg] = rsqrtf(qq*0.015625f - mn*mn + 1e-5f);
    }
    #pragma unroll
    for (int nt = 0; nt < 4; ++nt) {
      int col = nt*16 + lr;
      float gg = g1[col], bb = be1[col];
      #pragma unroll
      for (int reg = 0; reg < 4; ++reg) {
        int row = band + lg*4 + reg;
        float h1 = (comb[nt][reg]-mean1[reg])*rstd1[reg]*gg + bb;
        HsB[row*72 + col] = f2bf(h1);
      }
    }
  }
  __syncthreads();

  // ---- FFN1: h1 @ W1 (64->128) + relu -> HidB ----
  {
    f32x4 fa[8];
    #pragma unroll
    for (int nt = 0; nt < 8; ++nt) fa[nt] = zf4();
    #pragma unroll
    for (int ks = 0; ks < 2; ++ks) {
      bf16x8 a = ldfrag(HsB + (band + lr)*72 + ks*32 + lg*8);
      #pragma unroll
      for (int nt = 0; nt < 8; ++nt)
        fa[nt] = MFMA16(a, ldfrag(wB + 20480 + ((ks*8+nt)*64 + l)*8), fa[nt]);
    }
    #pragma unroll
    for (int nt = 0; nt < 8; ++nt) {
      int col = nt*16 + lr;
      float b1c = b1[col];
      #pragma unroll
      for (int reg = 0; reg < 4; ++reg) {
        int row = band + lg*4 + reg;
        HidB[row*136 + col] = f2bf(fmaxf(fa[nt][reg] + b1c, 0.f));
      }
    }
  }
  __syncthreads();

  // ---- FFN2 + residual(h1 bf16) -> LN2 -> out (+pool partials) ----
  {
    f32x4 f2[4];
    #pragma unroll
    for (int nt = 0; nt < 4; ++nt) f2[nt] = zf4();
    #pragma unroll
    for (int ks = 0; ks < 4; ++ks) {
      bf16x8 a = ldfrag(HidB + (band + lr)*136 + ks*32 + lg*8);
      #pragma unroll
      for (int nt = 0; nt < 4; ++nt)
        f2[nt] = MFMA16(a, ldfrag(wB + 28672 + ((ks*4+nt)*64 + l)*8), f2[nt]);
    }
    float c2[4][4];
    #pragma unroll
    for (int nt = 0; nt < 4; ++nt) {
      int col = nt*16 + lr;
      float b2c = b2[col];
      #pragma unroll
      for (int reg = 0; reg < 4; ++reg) {
        int row = band + lg*4 + reg;
        c2[nt][reg] = f2[nt][reg] + b2c + bf2f(HsB[row*72 + col]);
      }
    }
    float mean2[4], rstd2[4];
    #pragma unroll
    for (int reg = 0; reg < 4; ++reg) {
      float s = c2[0][reg]+c2[1][reg]+c2[2][reg]+c2[3][reg];
      float qq = c2[0][reg]*c2[0][reg]+c2[1][reg]*c2[1][reg]
               + c2[2][reg]*c2[2][reg]+c2[3][reg]*c2[3][reg];
      s += __shfl_xor(s,1); qq += __shfl_xor(qq,1);
      s += __shfl_xor(s,2); qq += __shfl_xor(qq,2);
      s += __shfl_xor(s,4); qq += __shfl_xor(qq,4);
      s += __shfl_xor(s,8); qq += __shfl_xor(qq,8);
      float mn = s*0.015625f;
      mean2[reg] = mn;
      rstd2[reg] = rsqrtf(qq*0.015625f - mn*mn + 1e-5f);
    }
    __syncthreads();
    #pragma unroll
    for (int nt = 0; nt < 4; ++nt) {
      int col = nt*16 + lr;
      float gg = g2[col], bb = be2[col];
      float part = 0.f;
      #pragma unroll
      for (int reg = 0; reg < 4; ++reg) {
        int row = band + lg*4 + reg;
        float y = (c2[nt][reg]-mean2[reg])*rstd2[reg]*gg + bb;
        if (OUT_BF16) Y16[(n0 + row)*64 + col] = f2bf(y);
        else          Y[(n0 + row)*64 + col] = y;
        part += y;
      }
      red[col*17 + w*4 + lg] = part;
    }
  }
  __syncthreads();
  if (t < 64) {
    float s = 0.f;
    #pragma unroll
    for (int g = 0; g < 16; ++g) s += red[t*17 + g];
    pp[(size_t)blockIdx.x*64 + t] = s;
  }
}

extern "C" void kernel_launch(void* const* d_in, const int* in_sizes, int n_in,
                              void* d_out, int out_size, void* d_ws, size_t ws_size,
                              hipStream_t stream) {
  (void)in_sizes; (void)n_in; (void)out_size; (void)ws_size;
  const float* x    = (const float*)d_in[0];
  const float* dck  = (const float*)d_in[1];
  const float* dcw1 = (const float*)d_in[2];
  const float* dcb1 = (const float*)d_in[3];
  const float* dcw2 = (const float*)d_in[4];
  const float* dcb2 = (const float*)d_in[5];
  const float* embw = (const float*)d_in[6];
  const float* embb = (const float*)d_in[7];
  const float* getvw= (const float*)d_in[8];
  const float* getvb= (const float*)d_in[9];
  const float* anb  = (const float*)d_in[10];
  // d_in[11] = na_bias: provably unused (softmax over size-1 axis == 1)
  const float* wq = (const float*)d_in[12]; const float* bq = (const float*)d_in[13];
  const float* wk = (const float*)d_in[14]; const float* bk = (const float*)d_in[15];
  const float* wv = (const float*)d_in[16]; const float* bv = (const float*)d_in[17];
  const float* wo = (const float*)d_in[18]; const float* bo = (const float*)d_in[19];
  const float* fw1= (const float*)d_in[20]; const float* fb1= (const float*)d_in[21];
  const float* fw2= (const float*)d_in[22]; const float* fb2= (const float*)d_in[23];
  const float* g1 = (const float*)d_in[24]; const float* be1= (const float*)d_in[25];
  const float* g2 = (const float*)d_in[26]; const float* be2= (const float*)d_in[27];

  float* out = (float*)d_out;
  float* ws  = (float*)d_ws;
  float* pp    = ws;                    // [16][64][64] (also 16-chunk pool for x)
  float* pm    = pp + 65536;            // [16][16][8]
  float* pe    = pm + 2048;
  float* pw    = pe + 2048;             // [16][16][8][64]
  float* attns = pw + 131072;           // [16][3][3] (pad 256)
  float* R0    = attns + 256;           // [16][3][3][64]
  float* T1    = R0 + 9216;             // [16][9][64]
  ushort* hB0  = (ushort*)(T1 + 9216);            // bf16 h buffers (8.4 MB each)
  ushort* hB1  = hB0 + (size_t)BB*LL*64;
  ushort* weffB= hB1 + (size_t)BB*LL*64;          // [3][16][12288]
  ushort* wsB  = weffB + (size_t)3*BB*12288;      // 3 x 36864
  ushort* wsE  = wsB + (size_t)3*36864;           // 4096

  dim3 blk(256);
  const int NT = BB*LL/64;  // 1024 row-tiles

  k_pack<<<dim3(160, 3), blk, 0, stream>>>(wq, wk, wv, getvw, wo, fw1, fw2, embw, wsB, wsE);
  k_pool_part<<<dim3(BB,16), blk, 0, stream>>>(x, pp);
  k_prep0<<<dim3(BB,3), blk, 0, stream>>>(pp, x, dck, R0);
  k_prep1<<<dim3(BB,9), blk, 0, stream>>>(R0, dck, T1);
  k_attns2<<<BB, blk, 0, stream>>>(pp, R0, T1, dcw1, dcb1, dcw2, dcb2, attns);
  k_wefff<<<dim3(BB,24), blk, 0, stream>>>(attns, dck, weffB);
  k_convF<<<dim3(BB,64), blk, 0, stream>>>(x, weffB, wsE, embb, hB0, pp);

  ushort* h  = hB0;
  ushort* hn = hB1;
  for (int i = 0; i < 3; ++i) {
    k_agent2<<<dim3(BB,16), blk, 0, stream>>>(h, anb + (size_t)i*8*4096, pp, pm, pe, pw);
    if (i == 2) {
      k_layer<false><<<NT, blk, 0, stream>>>(h, pm, pe, pw, getvw + i*4096, getvb + i*64,
                                             wsB + (size_t)i*36864,
                                             bq + i*64, bk + i*64, bv + i*64, bo + i*64,
                                             g1 + i*64, be1 + i*64, fb1 + i*128, fb2 + i*64,
                                             g2 + i*64, be2 + i*64, out, nullptr, pp);
    } else {
      k_layer<true><<<NT, blk, 0, stream>>>(h, pm, pe, pw, getvw + i*4096, getvb + i*64,
                                            wsB + (size_t)i*36864,
                                            bq + i*64, bk + i*64, bv + i*64, bo + i*64,
                                            g1 + i*64, be1 + i*64, fb1 + i*128, fb2 + i*64,
                                            g2 + i*64, be2 + i*64, nullptr, hn, pp);
    }
    ushort* tmp = h; h = hn; hn = tmp;
  }
}

// Round 12
// 185.965 us; speedup vs baseline: 1.1352x; 1.0250x over previous
//
#include <hip/hip_runtime.h>

#define BB 16
#define LL 4096
#define DD 64
#define NCH 32          // agent chunks per batch (128 rows each)

typedef const float* __restrict__ cfp;
typedef float* __restrict__ fp;
typedef const ushort* __restrict__ cup;
typedef ushort* __restrict__ up;

typedef __attribute__((ext_vector_type(8))) short bf16x8;
typedef __attribute__((ext_vector_type(4))) float f32x4;
#define MFMA16(a, b, c) __builtin_amdgcn_mfma_f32_16x16x32_bf16(a, b, c, 0, 0, 0)

__device__ __forceinline__ f32x4 zf4(){ f32x4 z; z[0]=0.f; z[1]=0.f; z[2]=0.f; z[3]=0.f; return z; }

union frag_u { bf16x8 v; uint2 u2[2]; uint u[4]; };

__device__ __forceinline__ float4 ld4(const float* p){ return *reinterpret_cast<const float4*>(p); }

__device__ __forceinline__ ushort f2bf(float f){
  uint u = __float_as_uint(f);
  return (ushort)((u + 0x7FFFu + ((u >> 16) & 1u)) >> 16);   // RNE
}
__device__ __forceinline__ float bf2f(ushort u){
  return __uint_as_float(((uint)u) << 16);
}
__device__ __forceinline__ uint packf2(float a, float b){
  return (uint)f2bf(a) | ((uint)f2bf(b) << 16);
}
__device__ __forceinline__ uint2 pack4(float4 v){
  return make_uint2(packf2(v.x, v.y), packf2(v.z, v.w));
}
__device__ __forceinline__ bf16x8 ldfrag(const ushort* p){ return *reinterpret_cast<const bf16x8*>(p); }

// ---------------- setup: weight packing (blocks 0..479) + x pooling (480..735) ----------------
__global__ __launch_bounds__(256) void k_setup(cfp wq, cfp wk, cfp wv, cfp getv, cfp wo,
                                               cfp fw1, cfp fw2, cfp embw,
                                               up dst, up dstE, cfp x, fp pp) {
  int bx = blockIdx.x, t = threadIdx.x;
  if (bx < 480) {
    int layer = bx / 160;
    int e = (bx % 160)*256 + t;                  // e < 40960
    if (e >= 36864) {
      int rem = e - 36864;
      int j = rem & 7, lane = (rem >> 3) & 63, rest = rem >> 9;
      int nt = rest & 3, ks = rest >> 2;
      int k = ks*32 + ((lane >> 4) << 3) + j, n = nt*16 + (lane & 15);
      dstE[rem] = f2bf(embw[k*64 + n]);
      return;
    }
    const float* W; int N, rem;
    if (e < 20480) {
      int mm = e >> 12; rem = e & 4095;
      W = (mm==0?wq: mm==1?wk: mm==2?wv: mm==3?getv: wo) + layer*4096; N = 64;
    } else if (e < 28672) {
      rem = e - 20480; W = fw1 + layer*8192; N = 128;
    } else {
      rem = e - 28672; W = fw2 + layer*8192; N = 64;
    }
    int NT = N >> 4;
    int j = rem & 7, lane = (rem >> 3) & 63, rest = rem >> 9;
    int nt = rest % NT, ks = rest / NT;
    int k = ks*32 + ((lane >> 4) << 3) + j, n = nt*16 + (lane & 15);
    dst[(size_t)layer*36864 + e] = f2bf(W[(size_t)k*N + n]);
  } else {
    int idx = bx - 480;
    int b = idx >> 4, gblk = idx & 15;
    int c = t & 63, r = t >> 6;
    const float* base = x + ((size_t)b*LL + (size_t)gblk*256)*64;
    float acc = 0.f;
    for (int l = r; l < 256; l += 4) acc += base[(size_t)l*64 + c];
    __shared__ float red[4][64];
    red[r][c] = acc; __syncthreads();
    if (t < 64) pp[(b*16 + gblk)*64 + t] = red[0][t]+red[1][t]+red[2][t]+red[3][t];
  }
}

// ---------------- tiny MLP (pooled -> 3-way softmax attn), block-uniform ----------------
__device__ __forceinline__ void tiny_mlp3(int t, const float* __restrict__ pooled,
                                          cfp w1, cfp b1, cfp w2, cfp b2,
                                          float* attn, float* hdn) {
  if (t < 16) {
    float a = b1[t];
    for (int c = 0; c < 64; ++c) a += pooled[c]*w1[t*64 + c];
    hdn[t] = fmaxf(a, 0.f);
  }
  __syncthreads();
  if (t < 3) {
    float a = b2[t];
    for (int j = 0; j < 16; ++j) a += hdn[j]*w2[t*16 + j];
    attn[t] = a;
  }
  __syncthreads();
  if (t == 0) {
    float m = fmaxf(attn[0], fmaxf(attn[1], attn[2]));
    float e0 = __expf(attn[0]-m), e1 = __expf(attn[1]-m), e2 = __expf(attn[2]-m);
    float s = e0+e1+e2;
    attn[0]=e0/s; attn[1]=e1/s; attn[2]=e2/s;
  }
  __syncthreads();
}

// ---------------- parallel precompute, stage 0: R0[b][type][k][64] ----------------
__global__ __launch_bounds__(256) void k_prep0(cfp pp, cfp x, cfp dck, fp R0) {
  int b = blockIdx.x, k = blockIdx.y, t = threadIdx.x;
  __shared__ float S[64], e0v[64], e1v[64], em0[64], em1[64];
  __shared__ float redu[3][256];
  const float* xb = x + (size_t)b*LL*64;
  if (t < 64) {
    float s = 0.f;
    for (int g = 0; g < 16; ++g) s += pp[((size_t)b*16 + g)*64 + t];
    S[t] = s;
    e0v[t] = xb[t]; e1v[t] = xb[64 + t];
    em0[t] = xb[(size_t)(LL-2)*64 + t]; em1[t] = xb[(size_t)(LL-1)*64 + t];
  }
  __syncthreads();
  int co = t & 63, q = t >> 6;
  cfp kb = dck + (size_t)k*36864;
  float pS = 0.f, ph0 = 0.f, phm = 0.f;
  for (int ci = q*16; ci < q*16 + 16; ++ci) {
    size_t base = ((size_t)co*64 + ci)*9 + 1;
    float w0 = kb[base], w1 = kb[base+3], w2 = kb[base+6];
    pS  += w0*(S[ci]-em1[ci]) + w1*S[ci] + w2*(S[ci]-e0v[ci]);
    ph0 += w1*e0v[ci] + w2*e1v[ci];
    phm += w0*em0[ci] + w1*em1[ci];
  }
  redu[0][t] = pS; redu[1][t] = ph0; redu[2][t] = phm;
  __syncthreads();
  if (t < 64) {
    R0[((b*3 + 0)*3 + k)*64 + t] = redu[0][t]+redu[0][64+t]+redu[0][128+t]+redu[0][192+t];
    R0[((b*3 + 1)*3 + k)*64 + t] = redu[1][t]+redu[1][64+t]+redu[1][128+t]+redu[1][192+t];
    R0[((b*3 + 2)*3 + k)*64 + t] = redu[2][t]+redu[2][64+t]+redu[2][128+t]+redu[2][192+t];
  }
}

// ---------------- parallel precompute, stage 1: T1[b][k*3+k0][64] ----------------
__global__ __launch_bounds__(256) void k_prep1(cfp R0, cfp dck, fp T1) {
  int b = blockIdx.x, k = blockIdx.y / 3, k0 = blockIdx.y % 3, t = threadIdx.x;
  __shared__ float u0[64], u1[64], u2[64];
  __shared__ float redu[256];
  if (t < 64) {
    float rs  = R0[((b*3 + 0)*3 + k0)*64 + t];
    float rh0 = R0[((b*3 + 1)*3 + k0)*64 + t];
    float rhm = R0[((b*3 + 2)*3 + k0)*64 + t];
    u0[t] = rs - rhm; u1[t] = rs; u2[t] = rs - rh0;
  }
  __syncthreads();
  int co = t & 63, q = t >> 6;
  cfp kb = dck + 110592 + (size_t)k*36864;
  float pS = 0.f;
  for (int ci = q*16; ci < q*16 + 16; ++ci) {
    size_t base = ((size_t)co*64 + ci)*9 + 1;
    pS += kb[base]*u0[ci] + kb[base+3]*u1[ci] + kb[base+6]*u2[ci];
  }
  redu[t] = pS;
  __syncthreads();
  if (t < 64)
    T1[((size_t)b*9 + blockIdx.y)*64 + t] = redu[t]+redu[64+t]+redu[128+t]+redu[192+t];
}

// ---------------- tiny serial chain: 3 MLPs over precomputed reductions ----------------
__global__ __launch_bounds__(256) void k_attns2(cfp pp, cfp R0, cfp T1,
                                                cfp dcw1, cfp dcb1, cfp dcw2, cfp dcb2,
                                                fp attns) {
  int b = blockIdx.x, t = threadIdx.x;
  __shared__ float pooled[64], hdn[16], attn[3], a0s[3], a1s[3];
  if (t < 64) {
    float s = 0.f;
    for (int g = 0; g < 16; ++g) s += pp[((size_t)b*16 + g)*64 + t];
    pooled[t] = s * (1.f/4096.f);
  }
  __syncthreads();
  tiny_mlp3(t, pooled, dcw1, dcb1, dcw2, dcb2, attn, hdn);
  if (t < 3) { attns[b*9 + t] = attn[t]; a0s[t] = attn[t]; }
  __syncthreads();
  if (t < 64) {
    float sn = a0s[0]*R0[((b*3+0)*3 + 0)*64 + t]
             + a0s[1]*R0[((b*3+0)*3 + 1)*64 + t]
             + a0s[2]*R0[((b*3+0)*3 + 2)*64 + t];
    pooled[t] = sn * (1.f/4096.f);
  }
  __syncthreads();
  tiny_mlp3(t, pooled, dcw1+1024, dcb1+16, dcw2+48, dcb2+3, attn, hdn);
  if (t < 3) { attns[b*9 + 3 + t] = attn[t]; a1s[t] = attn[t]; }
  __syncthreads();
  if (t < 64) {
    float s2 = 0.f;
    #pragma unroll
    for (int k = 0; k < 3; ++k)
      #pragma unroll
      for (int k0 = 0; k0 < 3; ++k0)
        s2 += a1s[k]*a0s[k0]*T1[((size_t)b*9 + k*3 + k0)*64 + t];
    pooled[t] = s2 * (1.f/4096.f);
  }
  __syncthreads();
  tiny_mlp3(t, pooled, dcw1+2048, dcb1+32, dcw2+96, dcb2+6, attn, hdn);
  if (t < 3) attns[b*9 + 6 + t] = attn[t];
}

// ---------------- effective-kernel fragment writer (all 3 stages) ----------------
__global__ __launch_bounds__(256) void k_wefff(cfp attns, cfp dck, up weffB) {
  int b = blockIdx.x, stage = blockIdx.y >> 3, slice = blockIdx.y & 7, t = threadIdx.x;
  float a0 = attns[b*9 + stage*3 + 0];
  float a1 = attns[b*9 + stage*3 + 1];
  float a2 = attns[b*9 + stage*3 + 2];
  cfp kern = dck + (size_t)stage*110592;
  int e0i = slice*1536;
  for (int e = e0i + t; e < e0i + 1536; e += 256) {
    int j = e & 7, lane = (e >> 3) & 63, nt = (e >> 9) & 3, ks = e >> 11;
    int k = ks*32 + ((lane >> 4) << 3) + j;
    int co = nt*16 + (lane & 15);
    int kh = k >> 6, ci = k & 63;
    size_t base = ((size_t)co*64 + ci)*9 + kh*3 + 1;     // kw=1 only (W=1 with pad)
    float v = a0*kern[base] + a1*kern[base + 36864] + a2*kern[base + 2*36864];
    weffB[((size_t)stage*16 + b)*12288 + e] = f2bf(v);
  }
}

// ---------------- conv MFMA core ----------------
__device__ __forceinline__ void conv_mfma(const ushort* Ts, const ushort* wb,
                                          int band, int lr, int lg, int l, f32x4 acc[4]) {
  #pragma unroll
  for (int nt = 0; nt < 4; ++nt) acc[nt] = zf4();
  #pragma unroll
  for (int ks = 0; ks < 6; ++ks) {
    int k8 = ks*32 + lg*8;
    int kh = k8 >> 6, ci = k8 & 63;
    bf16x8 a = ldfrag(Ts + (band + lr + kh)*72 + ci);
    #pragma unroll
    for (int nt = 0; nt < 4; ++nt)
      acc[nt] = MFMA16(a, ldfrag(wb + ((ks*4+nt)*64 + l)*8), acc[nt]);
  }
}

// ---------------- fused conv stem: 3 dynamic-conv stages + emb GEMM, halo'd ----------------
__global__ __launch_bounds__(256) void k_convF(cfp x, cup weffB, cup wE, cfp embb,
                                               up houtB, fp pp) {
  int b = blockIdx.x, wblk = blockIdx.y, t = threadIdx.x;
  int n0 = wblk*64;
  __shared__ ushort TsA[84*72];
  __shared__ ushort TsB[84*72];
  __shared__ float red[64*17];
  int w = t >> 6, l = t & 63, lr = l & 15, lg = l >> 4;

  for (int idx = t; idx < 1344; idx += 256) {
    int r = idx >> 4, c4 = (idx & 15)*4;
    int g = n0 - 4 + r;
    float4 v = make_float4(0.f,0.f,0.f,0.f);
    if (r >= 1 && r <= 70 && g >= 0 && g < LL) v = ld4(x + ((size_t)b*LL + g)*64 + c4);
    *(uint2*)(TsA + r*72 + c4) = pack4(v);
  }
  for (int idx = t; idx < 32; idx += 256) {       // zero TsB guard rows 82,83
    int r = 82 + (idx >> 4), c4 = (idx & 15)*4;
    *(uint2*)(TsB + r*72 + c4) = make_uint2(0u,0u);
  }
  __syncthreads();

  // ---- stage 0: TsA -> TsB (zero-force rows outside [0,LL)) ----
  {
    const ushort* wb = weffB + (size_t)b*12288;
    for (int bi = w; bi < 5; bi += 4) {
      int band = 2 + bi*16;
      f32x4 acc[4];
      conv_mfma(TsA, wb, band - 1, lr, lg, l, acc);
      #pragma unroll
      for (int nt = 0; nt < 4; ++nt)
        #pragma unroll
        for (int reg = 0; reg < 4; ++reg) {
          int row = band + lg*4 + reg;
          int g = n0 - 4 + row;
          float v = (g >= 0 && g < LL) ? acc[nt][reg] : 0.f;
          TsB[row*72 + nt*16 + lr] = f2bf(v);
        }
    }
  }
  __syncthreads();
  // ---- stage 1: TsB -> TsA (zero-force rows outside [0,LL)) ----
  {
    const ushort* wb = weffB + (size_t)(16 + b)*12288;
    for (int bi = w; bi < 5; bi += 4) {
      int band = 3 + bi*16;
      f32x4 acc[4];
      conv_mfma(TsB, wb, band - 1, lr, lg, l, acc);
      #pragma unroll
      for (int nt = 0; nt < 4; ++nt)
        #pragma unroll
        for (int reg = 0; reg < 4; ++reg) {
          int row = band + lg*4 + reg;
          int g = n0 - 4 + row;
          float v = (g >= 0 && g < LL) ? acc[nt][reg] : 0.f;
          TsA[row*72 + nt*16 + lr] = f2bf(v);
        }
    }
  }
  __syncthreads();
  // ---- stage 2: TsA -> TsB (exactly 4 bands, all in-range) ----
  {
    const ushort* wb = weffB + (size_t)(32 + b)*12288;
    int band = 4 + w*16;
    f32x4 acc[4];
    conv_mfma(TsA, wb, band - 1, lr, lg, l, acc);
    #pragma unroll
    for (int nt = 0; nt < 4; ++nt)
      #pragma unroll
      for (int reg = 0; reg < 4; ++reg)
        TsB[(band + lg*4 + reg)*72 + nt*16 + lr] = f2bf(acc[nt][reg]);
  }
  __syncthreads();
  // ---- emb GEMM on stage-2 rows; bounce via TsA for coalesced store ----
  {
    int band = 4 + w*16;
    f32x4 ea[4];
    #pragma unroll
    for (int nt = 0; nt < 4; ++nt) ea[nt] = zf4();
    #pragma unroll
    for (int ks = 0; ks < 2; ++ks) {
      bf16x8 a = ldfrag(TsB + (band + lr)*72 + ks*32 + lg*8);
      #pragma unroll
      for (int nt = 0; nt < 4; ++nt)
        ea[nt] = MFMA16(a, ldfrag(wE + ((ks*4+nt)*64 + l)*8), ea[nt]);
    }
    #pragma unroll
    for (int nt = 0; nt < 4; ++nt) {
      int col = nt*16 + lr;
      float bc = embb[col], part = 0.f;
      #pragma unroll
      for (int reg = 0; reg < 4; ++reg) {
        int row = band + lg*4 + reg;
        float y = ea[nt][reg] + bc;
        TsA[row*72 + col] = f2bf(y);
        part += y;
      }
      red[col*17 + w*4 + lg] = part;
    }
  }
  __syncthreads();
  for (int idx = t; idx < 512; idx += 256) {
    int r = idx >> 3, c8 = (idx & 7)*8;
    *(uint4*)(houtB + ((size_t)b*LL + n0 + r)*64 + c8) = *(const uint4*)(TsA + (r+4)*72 + c8);
  }
  if (t < 64) {
    float s = 0.f;
    #pragma unroll
    for (int g = 0; g < 16; ++g) s += red[t*17 + g];
    pp[((size_t)b*64 + wblk)*64 + t] = s;
  }
}

// ---------------- agent attention: 128-row chunks (2 blocks/CU) ----------------
__global__ __launch_bounds__(256) void k_agent2(cup h16, cfp anb, cfp pp,
                                                fp pm, fp pe, fp pw) {
  int b = blockIdx.x, ch = blockIdx.y, t = threadIdx.x;
  int w = t >> 6, l = t & 63;
  __shared__ float means_s[64];
  __shared__ float sc[8][130];
  __shared__ float red4[4][64];
  __shared__ float esp[8][33];
  __shared__ float mcs[8], ess[8];
  __shared__ float wred[4][8][64];
  {
    float acc = 0.f;
    for (int c = w; c < 64; c += 4) acc += pp[((size_t)b*64 + c)*64 + l];
    red4[w][l] = acc;
  }
  __syncthreads();
  if (t < 64) means_s[t] = (red4[0][t]+red4[1][t]+red4[2][t]+red4[3][t])
                           * (1.f/4096.f) * 0.35355339059327373f;
  __syncthreads();
  const ushort* hb = h16 + ((size_t)b*LL + (size_t)ch*128)*64;
  int g8 = l >> 3, k8 = l & 7;
  float ms8[8];
  #pragma unroll
  for (int j = 0; j < 8; ++j) ms8[j] = means_s[k8*8 + j];
  #pragma unroll
  for (int it = 0; it < 4; ++it) {
    int n = w*32 + it*8 + g8;
    uint4 hv = *(const uint4*)(hb + (size_t)n*64 + k8*8);
    float d = bf2f((ushort)(hv.x & 0xffffu))*ms8[0] + bf2f((ushort)(hv.x >> 16))*ms8[1]
            + bf2f((ushort)(hv.y & 0xffffu))*ms8[2] + bf2f((ushort)(hv.y >> 16))*ms8[3]
            + bf2f((ushort)(hv.z & 0xffffu))*ms8[4] + bf2f((ushort)(hv.z >> 16))*ms8[5]
            + bf2f((ushort)(hv.w & 0xffffu))*ms8[6] + bf2f((ushort)(hv.w >> 16))*ms8[7];
    sc[k8][n] = d;
  }
  __syncthreads();
  int hh = t >> 5, j0 = (t & 31) * 4;
  const float* ab = anb + (size_t)hh*LL + ch*128 + j0;
  float loc[4];
  float mx = -1e30f;
  #pragma unroll
  for (int k = 0; k < 4; ++k) {
    loc[k] = sc[hh][j0 + k] + ab[k];
    mx = fmaxf(mx, loc[k]);
  }
  esp[hh][t & 31] = mx;
  __syncthreads();
  if (t < 8) {
    float m = -1e30f;
    for (int k = 0; k < 32; ++k) m = fmaxf(m, esp[t][k]);
    mcs[t] = m;
  }
  __syncthreads();
  {
    float M = mcs[hh], s = 0.f;
    #pragma unroll
    for (int k = 0; k < 4; ++k) {
      float e = __expf(loc[k] - M);
      sc[hh][j0 + k] = e;
      s += e;
    }
    esp[hh][t & 31] = s;
  }
  __syncthreads();
  if (t < 8) {
    float s = 0.f;
    for (int k = 0; k < 32; ++k) s += esp[t][k];
    ess[t] = s;
  }
  float acc8[8] = {};
  for (int i = 0; i < 32; ++i) {
    int n = w*32 + i;
    float xv = bf2f(hb[(size_t)n*64 + l]);
    #pragma unroll
    for (int q = 0; q < 8; ++q) acc8[q] = fmaf(sc[q][n], xv, acc8[q]);
  }
  __syncthreads();
  #pragma unroll
  for (int q = 0; q < 8; ++q) wred[w][q][l] = acc8[q];
  __syncthreads();
  for (int o = t; o < 512; o += 256) {
    int q = o >> 6, ll = o & 63;
    pw[(((size_t)b*NCH + ch)*8 + q)*64 + ll] =
        wred[0][q][ll]+wred[1][q][ll]+wred[2][q][ll]+wred[3][q][ll];
  }
  if (t < 8) {
    pe[((size_t)b*NCH + ch)*8 + t] = ess[t];
    pm[((size_t)b*NCH + ch)*8 + t] = mcs[t];
  }
}

// ---------------- agent finalize: merge chunks + getv projection -> agv[b][64] ----------------
__global__ __launch_bounds__(256) void k_agfin(cfp pm, cfp pe, cfp pw,
                                               cfp getv, cfp getvb, fp agv) {
  int b = blockIdx.x, t = threadIdx.x;
  __shared__ float wm[8][65];
  __shared__ float Ms[8], den[8];
  if (t < 8) {
    float M = -1e30f;
    for (int c = 0; c < NCH; ++c) M = fmaxf(M, pm[((size_t)b*NCH+c)*8 + t]);
    float d = 0.f;
    for (int c = 0; c < NCH; ++c)
      d += pe[((size_t)b*NCH+c)*8 + t] * __expf(pm[((size_t)b*NCH+c)*8 + t] - M);
    Ms[t] = M; den[t] = d;
  }
  __syncthreads();
  for (int o = t; o < 512; o += 256) {
    int q = o >> 6, l = o & 63;
    float M = Ms[q], s = 0.f;
    for (int c = 0; c < NCH; ++c)
      s += pw[(((size_t)b*NCH+c)*8 + q)*64 + l] * __expf(pm[((size_t)b*NCH+c)*8 + q] - M);
    wm[q][l] = s / den[q];
  }
  __syncthreads();
  if (t < 64) {
    int q = t >> 3;
    float a = getvb[t];
    for (int c = 0; c < 64; ++c) a = fmaf(wm[q][c], getv[c*64 + t], a);
    agv[b*64 + t] = a;
  }
}

// ================= fused layer kernel (all-MFMA, bf16 in; templated out) =================
template<bool OUT_BF16>
__global__ __launch_bounds__(256, 4) void k_layer(
    cup h16, cfp agv, cfp getvb, cup wB,
    cfp bq, cfp bk, cfp bv, cfp bo,
    cfp g1, cfp be1, cfp b1, cfp b2, cfp g2, cfp be2,
    fp Y, up Y16, fp pp) {
  __shared__ float smem[9984];           // 39936 B -> 4 blocks/CU
  ushort* HsB  = (ushort*)(smem);        // [64][72]
  ushort* Qp   = (ushort*)(smem + 2304); // [4][64][20]
  ushort* Kp   = (ushort*)(smem + 4864); // [4][64][20]
  ushort* Vt   = (ushort*)(smem + 7424); // [4][16][72]
  float*  sums = smem + 9728;            // [4][64]
  ushort* OB   = (ushort*)(smem + 7424); // aliases Vt
  float*  red  = smem + 7424;            // aliases Vt/OB
  ushort* HidB = (ushort*)(smem + 2304); // aliases Qp+Kp

  int t = threadIdx.x;
  size_t n0 = (size_t)blockIdx.x*64;
  int b = (int)(n0 >> 12);
  int w = t >> 6, l = t & 63, band = w*16, lr = l & 15, lg = l >> 4;

  #pragma unroll
  for (int it = 0; it < 2; ++it) {
    int idx = it*256 + t, r = idx >> 3, c8 = (idx & 7)*8;
    *(uint4*)(HsB + r*72 + c8) = *(const uint4*)(h16 + (n0 + r)*64 + c8);
  }
  __syncthreads();

  // ---- Q,K,V,lepe MFMA GEMMs ----
  f32x4 ka[4], va[4], qa[4], la[4];
  #pragma unroll
  for (int nt = 0; nt < 4; ++nt) {
    ka[nt] = zf4(); va[nt] = zf4(); qa[nt] = zf4(); la[nt] = zf4();
  }
  #pragma unroll
  for (int ks = 0; ks < 2; ++ks) {
    bf16x8 a = ldfrag(HsB + (band + lr)*72 + ks*32 + lg*8);
    #pragma unroll
    for (int nt = 0; nt < 4; ++nt) {
      int fo = ((ks*4 + nt)*64 + l)*8;
      qa[nt] = MFMA16(a, ldfrag(wB + fo),         qa[nt]);
      ka[nt] = MFMA16(a, ldfrag(wB + 4096 + fo),  ka[nt]);
      va[nt] = MFMA16(a, ldfrag(wB + 8192 + fo),  va[nt]);
      la[nt] = MFMA16(a, ldfrag(wB + 12288 + fo), la[nt]);
    }
  }
  #pragma unroll
  for (int nt = 0; nt < 4; ++nt) {
    int col = nt*16 + lr;
    float bkc = bk[col], bvc = bv[col], bqc = bq[col];
    #pragma unroll
    for (int reg = 0; reg < 4; ++reg) {
      int tok = band + 4*lg + reg;
      Kp[nt*1280 + tok*20 + lr] = f2bf(ka[nt][reg] + bkc);
      Qp[nt*1280 + tok*20 + lr] = f2bf((qa[nt][reg] + bqc) * 0.25f);
    }
    int tok0 = band + 4*lg;
    *(uint2*)(Vt + nt*1152 + lr*72 + tok0) =
        make_uint2(packf2(va[nt][0]+bvc, va[nt][1]+bvc),
                   packf2(va[nt][2]+bvc, va[nt][3]+bvc));
  }
  __syncthreads();

  // ---- windowed attention: wave = head; MFMA S^T = K*Q^T (slot-paired K_eff=16) ----
  {
    frag_u kaf[4], qbf[4], vbf[4], pf;
    #pragma unroll
    for (int tt = 0; tt < 4; ++tt) {
      kaf[tt].u2[0] = *(const uint2*)(Kp + w*1280 + (tt*16+lr)*20 + lg*4);
      kaf[tt].u[2] = 0; kaf[tt].u[3] = 0;
      qbf[tt].u2[0] = *(const uint2*)(Qp + w*1280 + (tt*16+lr)*20 + lg*4);
      qbf[tt].u[2] = 0; qbf[tt].u[3] = 0;
      vbf[tt].u2[0] = *(const uint2*)(Vt + w*1152 + lr*72 + tt*16 + lg*4);
      vbf[tt].u[2] = 0; vbf[tt].u[3] = 0;
    }
    f32x4 st[4][4];
    #pragma unroll
    for (int kt = 0; kt < 4; ++kt)
      #pragma unroll
      for (int qt = 0; qt < 4; ++qt) {
        f32x4 z = zf4();
        st[kt][qt] = MFMA16(kaf[kt].v, qbf[qt].v, z);
      }
    f32x4 oacc[4];
    #pragma unroll
    for (int qt = 0; qt < 4; ++qt) {
      float M = -1e30f;
      #pragma unroll
      for (int kt = 0; kt < 4; ++kt)
        #pragma unroll
        for (int reg = 0; reg < 4; ++reg) M = fmaxf(M, st[kt][qt][reg]);
      M = fmaxf(M, __shfl_xor(M, 16));
      M = fmaxf(M, __shfl_xor(M, 32));
      float s = 0.f;
      #pragma unroll
      for (int kt = 0; kt < 4; ++kt)
        #pragma unroll
        for (int reg = 0; reg < 4; ++reg) {
          float e = __expf(st[kt][qt][reg] - M);
          st[kt][qt][reg] = e; s += e;
        }
      s += __shfl_xor(s, 16);
      s += __shfl_xor(s, 32);
      if (lg == 0) sums[w*64 + qt*16 + lr] = s;
      oacc[qt] = zf4();
    }
    #pragma unroll
    for (int qt = 0; qt < 4; ++qt)
      #pragma unroll
      for (int kt = 0; kt < 4; ++kt) {
        pf.u[0] = packf2(st[kt][qt][0], st[kt][qt][1]);
        pf.u[1] = packf2(st[kt][qt][2], st[kt][qt][3]);
        pf.u[2] = 0; pf.u[3] = 0;
        oacc[qt] = MFMA16(pf.v, vbf[kt].v, oacc[qt]);
      }
    __syncthreads();
    #pragma unroll
    for (int qt = 0; qt < 4; ++qt)
      #pragma unroll
      for (int reg = 0; reg < 4; ++reg) {
        int q = qt*16 + 4*lg + reg;
        OB[q*72 + band + lr] = f2bf(oacc[qt][reg] / sums[w*64 + q]);
      }
  }
  __syncthreads();

  // ---- O@Wo + bo + agent(agv) + residual(h bf16) + lepe -> LN1 ----
  float comb[4][4];
  {
    f32x4 wa[4];
    #pragma unroll
    for (int nt = 0; nt < 4; ++nt) wa[nt] = zf4();
    #pragma unroll
    for (int ks = 0; ks < 2; ++ks) {
      bf16x8 a = ldfrag(OB + (band + lr)*72 + ks*32 + lg*8);
      #pragma unroll
      for (int nt = 0; nt < 4; ++nt)
        wa[nt] = MFMA16(a, ldfrag(wB + 16384 + ((ks*4+nt)*64 + l)*8), wa[nt]);
    }
    #pragma unroll
    for (int nt = 0; nt < 4; ++nt) {
      int col = nt*16 + lr;
      float cadd = bo[col] + agv[b*64 + col] + getvb[col];
      #pragma unroll
      for (int reg = 0; reg < 4; ++reg) {
        int row = band + lg*4 + reg;
        comb[nt][reg] = wa[nt][reg] + la[nt][reg] + cadd + bf2f(HsB[row*72 + col]);
      }
    }
  }
  {
    float mean1[4], rstd1[4];
    #pragma unroll
    for (int reg = 0; reg < 4; ++reg) {
      float s = comb[0][reg]+comb[1][reg]+comb[2][reg]+comb[3][reg];
      float qq = comb[0][reg]*comb[0][reg]+comb[1][reg]*comb[1][reg]
               + comb[2][reg]*comb[2][reg]+comb[3][reg]*comb[3][reg];
      s += __shfl_xor(s,1); qq += __shfl_xor(qq,1);
      s += __shfl_xor(s,2); qq += __shfl_xor(qq,2);
      s += __shfl_xor(s,4); qq += __shfl_xor(qq,4);
      s += __shfl_xor(s,8); qq += __shfl_xor(qq,8);
      float mn = s*0.015625f;
      mean1[reg] = mn;
      rstd1[reg] = rsqrtf(qq*0.015625f - mn*mn + 1e-5f);
    }
    #pragma unroll
    for (int nt = 0; nt < 4; ++nt) {
      int col = nt*16 + lr;
      float gg = g1[col], bb = be1[col];
      #pragma unroll
      for (int reg = 0; reg < 4; ++reg) {
        int row = band + lg*4 + reg;
        float h1 = (comb[nt][reg]-mean1[reg])*rstd1[reg]*gg + bb;
        HsB[row*72 + col] = f2bf(h1);
      }
    }
  }
  __syncthreads();

  // ---- FFN1: h1 @ W1 (64->128) + relu -> HidB ----
  {
    f32x4 fa[8];
    #pragma unroll
    for (int nt = 0; nt < 8; ++nt) fa[nt] = zf4();
    #pragma unroll
    for (int ks = 0; ks < 2; ++ks) {
      bf16x8 a = ldfrag(HsB + (band + lr)*72 + ks*32 + lg*8);
      #pragma unroll
      for (int nt = 0; nt < 8; ++nt)
        fa[nt] = MFMA16(a, ldfrag(wB + 20480 + ((ks*8+nt)*64 + l)*8), fa[nt]);
    }
    #pragma unroll
    for (int nt = 0; nt < 8; ++nt) {
      int col = nt*16 + lr;
      float b1c = b1[col];
      #pragma unroll
      for (int reg = 0; reg < 4; ++reg) {
        int row = band + lg*4 + reg;
        HidB[row*136 + col] = f2bf(fmaxf(fa[nt][reg] + b1c, 0.f));
      }
    }
  }
  __syncthreads();

  // ---- FFN2 + residual(h1 bf16) -> LN2 -> out (+pool partials unless final) ----
  {
    f32x4 f2[4];
    #pragma unroll
    for (int nt = 0; nt < 4; ++nt) f2[nt] = zf4();
    #pragma unroll
    for (int ks = 0; ks < 4; ++ks) {
      bf16x8 a = ldfrag(HidB + (band + lr)*136 + ks*32 + lg*8);
      #pragma unroll
      for (int nt = 0; nt < 4; ++nt)
        f2[nt] = MFMA16(a, ldfrag(wB + 28672 + ((ks*4+nt)*64 + l)*8), f2[nt]);
    }
    float c2[4][4];
    #pragma unroll
    for (int nt = 0; nt < 4; ++nt) {
      int col = nt*16 + lr;
      float b2c = b2[col];
      #pragma unroll
      for (int reg = 0; reg < 4; ++reg) {
        int row = band + lg*4 + reg;
        c2[nt][reg] = f2[nt][reg] + b2c + bf2f(HsB[row*72 + col]);
      }
    }
    float mean2[4], rstd2[4];
    #pragma unroll
    for (int reg = 0; reg < 4; ++reg) {
      float s = c2[0][reg]+c2[1][reg]+c2[2][reg]+c2[3][reg];
      float qq = c2[0][reg]*c2[0][reg]+c2[1][reg]*c2[1][reg]
               + c2[2][reg]*c2[2][reg]+c2[3][reg]*c2[3][reg];
      s += __shfl_xor(s,1); qq += __shfl_xor(qq,1);
      s += __shfl_xor(s,2); qq += __shfl_xor(qq,2);
      s += __shfl_xor(s,4); qq += __shfl_xor(qq,4);
      s += __shfl_xor(s,8); qq += __shfl_xor(qq,8);
      float mn = s*0.015625f;
      mean2[reg] = mn;
      rstd2[reg] = rsqrtf(qq*0.015625f - mn*mn + 1e-5f);
    }
    if (OUT_BF16) __syncthreads();     // HidB reads done; red (alias Vt) free
    #pragma unroll
    for (int nt = 0; nt < 4; ++nt) {
      int col = nt*16 + lr;
      float gg = g2[col], bb = be2[col];
      float part = 0.f;
      #pragma unroll
      for (int reg = 0; reg < 4; ++reg) {
        int row = band + lg*4 + reg;
        float y = (c2[nt][reg]-mean2[reg])*rstd2[reg]*gg + bb;
        if (OUT_BF16) Y16[(n0 + row)*64 + col] = f2bf(y);
        else          Y[(n0 + row)*64 + col] = y;
        part += y;
      }
      if (OUT_BF16) red[col*17 + w*4 + lg] = part;
    }
  }
  if (OUT_BF16) {
    __syncthreads();
    if (t < 64) {
      float s = 0.f;
      #pragma unroll
      for (int g = 0; g < 16; ++g) s += red[t*17 + g];
      pp[(size_t)blockIdx.x*64 + t] = s;
    }
  }
}

extern "C" void kernel_launch(void* const* d_in, const int* in_sizes, int n_in,
                              void* d_out, int out_size, void* d_ws, size_t ws_size,
                              hipStream_t stream) {
  (void)in_sizes; (void)n_in; (void)out_size; (void)ws_size;
  const float* x    = (const float*)d_in[0];
  const float* dck  = (const float*)d_in[1];
  const float* dcw1 = (const float*)d_in[2];
  const float* dcb1 = (const float*)d_in[3];
  const float* dcw2 = (const float*)d_in[4];
  const float* dcb2 = (const float*)d_in[5];
  const float* embw = (const float*)d_in[6];
  const float* embb = (const float*)d_in[7];
  const float* getvw= (const float*)d_in[8];
  const float* getvb= (const float*)d_in[9];
  const float* anb  = (const float*)d_in[10];
  // d_in[11] = na_bias: provably unused (softmax over size-1 axis == 1)
  const float* wq = (const float*)d_in[12]; const float* bq = (const float*)d_in[13];
  const float* wk = (const float*)d_in[14]; const float* bk = (const float*)d_in[15];
  const float* wv = (const float*)d_in[16]; const float* bv = (const float*)d_in[17];
  const float* wo = (const float*)d_in[18]; const float* bo = (const float*)d_in[19];
  const float* fw1= (const float*)d_in[20]; const float* fb1= (const float*)d_in[21];
  const float* fw2= (const float*)d_in[22]; const float* fb2= (const float*)d_in[23];
  const float* g1 = (const float*)d_in[24]; const float* be1= (const float*)d_in[25];
  const float* g2 = (const float*)d_in[26]; const float* be2= (const float*)d_in[27];

  float* out = (float*)d_out;
  float* ws  = (float*)d_ws;
  float* pp    = ws;                    // [16][64][64] (also 16-chunk pool for x)
  float* pm    = pp + 65536;            // [16][32][8]
  float* pe    = pm + 4096;
  float* pw    = pe + 4096;             // [16][32][8][64]
  float* agv   = pw + 262144;           // [16][64]
  float* attns = agv + 1024;            // [16][9] (pad 256)
  float* R0    = attns + 256;           // [16][3][3][64]
  float* T1    = R0 + 9216;             // [16][9][64]
  ushort* hB0  = (ushort*)(T1 + 9216);            // bf16 h buffers (8.4 MB each)
  ushort* hB1  = hB0 + (size_t)BB*LL*64;
  ushort* weffB= hB1 + (size_t)BB*LL*64;          // [3][16][12288]
  ushort* wsB  = weffB + (size_t)3*BB*12288;      // 3 x 36864
  ushort* wsE  = wsB + (size_t)3*36864;           // 4096

  dim3 blk(256);
  const int NT = BB*LL/64;  // 1024 row-tiles

  k_setup<<<736, blk, 0, stream>>>(wq, wk, wv, getvw, wo, fw1, fw2, embw, wsB, wsE, x, pp);
  k_prep0<<<dim3(BB,3), blk, 0, stream>>>(pp, x, dck, R0);
  k_prep1<<<dim3(BB,9), blk, 0, stream>>>(R0, dck, T1);
  k_attns2<<<BB, blk, 0, stream>>>(pp, R0, T1, dcw1, dcb1, dcw2, dcb2, attns);
  k_wefff<<<dim3(BB,24), blk, 0, stream>>>(attns, dck, weffB);
  k_convF<<<dim3(BB,64), blk, 0, stream>>>(x, weffB, wsE, embb, hB0, pp);

  ushort* h  = hB0;
  ushort* hn = hB1;
  for (int i = 0; i < 3; ++i) {
    k_agent2<<<dim3(BB,NCH), blk, 0, stream>>>(h, anb + (size_t)i*8*4096, pp, pm, pe, pw);
    k_agfin<<<BB, blk, 0, stream>>>(pm, pe, pw, getvw + i*4096, getvb + i*64, agv);
    if (i == 2) {
      k_layer<false><<<NT, blk, 0, stream>>>(h, agv, getvb + i*64,
                                             wsB + (size_t)i*36864,
                                             bq + i*64, bk + i*64, bv + i*64, bo + i*64,
                                             g1 + i*64, be1 + i*64, fb1 + i*128, fb2 + i*64,
                                             g2 + i*64, be2 + i*64, out, nullptr, pp);
    } else {
      k_layer<true><<<NT, blk, 0, stream>>>(h, agv, getvb + i*64,
                                            wsB + (size_t)i*36864,
                                            bq + i*64, bk + i*64, bv + i*64, bo + i*64,
                                            g1 + i*64, be1 + i*64, fb1 + i*128, fb2 + i*64,
                                            g2 + i*64, be2 + i*64, nullptr, hn, pp);
    }
    ushort* tmp = h; h = hn; hn = tmp;
  }
}